// Round 3
// baseline (5405.102 us; speedup 1.0000x reference)
//
#include <hip/hip_runtime.h>
#include <cstdint>
#include <cstddef>

#define CIN 512
#define NA 36864           // 4096 positions * 9 anchors
#define NPRE 6000
#define NPOST 300
#define CBUF_CAP 8192
#define NWORD 94           // ceil(6000/64)
#define NEGV -1000000000.0f

// d_out float offsets (return-order concat)
#define O_LOCS   0
#define O_SCORES 1179648   // 8*36864*4
#define O_ROIS   1769472   // + 8*36864*2
#define O_RIDX   1779072   // + 8*300*4
#define O_ANCH   1781472   // + 8*300

// ---------- exact-rounding helpers (prevent FMA contraction where order matters) ----
__device__ __forceinline__ float fmulr(float a, float b) { return __fmul_rn(a, b); }
__device__ __forceinline__ float faddr(float a, float b) { return __fadd_rn(a, b); }
__device__ __forceinline__ float fsubr(float a, float b) { return __fsub_rn(a, b); }

__device__ __forceinline__ void anchor_for(int a, int pos, float* anc) {
    const double rat[3] = {0.5, 1.0, 2.0};
    const double scl[3] = {8.0, 16.0, 32.0};
    int ri = a / 3, si = a - ri * 3;
    double h = 16.0 * scl[si] * sqrt(rat[ri]);
    double w = 16.0 * scl[si] * sqrt(1.0 / rat[ri]);
    float a0 = (float)(8.0 - h * 0.5);
    float a1 = (float)(8.0 - w * 0.5);
    float a2 = (float)(8.0 + h * 0.5);
    float a3 = (float)(8.0 + w * 0.5);
    int y = pos >> 6, x = pos & 63;
    float sy = (float)(y * 16), sx = (float)(x * 16);
    anc[0] = faddr(a0, sy); anc[1] = faddr(a1, sx);
    anc[2] = faddr(a2, sy); anc[3] = faddr(a3, sx);
}

__device__ __forceinline__ bool decode_box(float4 L, const float* anc, float* box) {
    float ah  = fsubr(anc[2], anc[0]);
    float aw  = fsubr(anc[3], anc[1]);
    float acy = faddr(anc[0], fmulr(0.5f, ah));
    float acx = faddr(anc[1], fmulr(0.5f, aw));
    float cy  = faddr(fmulr(L.x, ah), acy);
    float cx  = faddr(fmulr(L.y, aw), acx);
    float h   = fmulr(ah, expf(L.z));
    float w   = fmulr(aw, expf(L.w));
    float y1 = fminf(fmaxf(fsubr(cy, fmulr(0.5f, h)), 0.0f), 1024.0f);
    float x1 = fminf(fmaxf(fsubr(cx, fmulr(0.5f, w)), 0.0f), 1024.0f);
    float y2 = fminf(fmaxf(faddr(cy, fmulr(0.5f, h)), 0.0f), 1024.0f);
    float x2 = fminf(fmaxf(faddr(cx, fmulr(0.5f, w)), 0.0f), 1024.0f);
    box[0] = y1; box[1] = x1; box[2] = y2; box[3] = x2;
    float hs = fsubr(y2, y1), ws2 = fsubr(x2, x1);
    return (hs >= 16.0f) && (ws2 >= 16.0f);
}

// monotonic 64-bit map of a double (totally ordered, sign handled)
__device__ __forceinline__ unsigned long long mono64(double f) {
    unsigned long long u = (unsigned long long)__double_as_longlong(f);
    return (u & 0x8000000000000000ull) ? ~u : (u | 0x8000000000000000ull);
}

// ---------------- weight reorder: w1[oc][c][ky][kx] -> wr[(c*9+tap)*512+oc] ----------
__global__ void k_wreord(const float* __restrict__ w1, float* __restrict__ wr) {
    int idx = blockIdx.x * 256 + threadIdx.x;
    if (idx >= 512 * 9 * 512) return;
    int oc  = idx & 511;
    int tap = (idx >> 9) % 9;
    int c   = idx / (512 * 9);
    wr[idx] = w1[(oc * 512 + c) * 9 + tap];
}

// ---------------- 3x3 conv 512->512 + bias + relu, f64 main accumulators -------------
// block: 32 oc x 4 rows x 64 cols, 256 threads; per-thread 4 oc x 8 cols.
// per-cc fp32 sub-accumulate (9 FMAs) merged into f64 -> conv error ~4e-8.
__global__ __launch_bounds__(256) void k_conv3(const float* __restrict__ x,
                                               const float* __restrict__ wr,
                                               const float* __restrict__ b1,
                                               float* __restrict__ mid) {
    __shared__ float in_s[8 * 6 * 68];   // [cc][rr(6)][xi(68)]  13056 floats
    __shared__ float w_s[8 * 9 * 32];    // [cc][tap][oc32]       2304 floats
    const int yb  = blockIdx.x;          // 16
    const int ocb = blockIdx.y;          // 16
    const int n   = blockIdx.z;          // 8
    const int t   = threadIdx.x;
    const int y0  = yb * 4;
    const int tocg = t >> 5;             // 0..7 -> oc group of 4
    const int tx   = t & 31;
    const int r    = tx >> 3;            // 0..3 row
    const int xo   = (tx & 7) << 3;      // 0..56 col octet

    double accd[4][8];
#pragma unroll
    for (int i = 0; i < 4; i++)
#pragma unroll
        for (int j = 0; j < 8; j++) accd[i][j] = 0.0;

    for (int ch = 0; ch < 64; ++ch) {
        const int c0 = ch * 8;
        for (int idx = t; idx < 2304; idx += 256) {
            int cc = idx / 288, rem = idx - cc * 288;
            int tap = rem >> 5, o = rem & 31;
            w_s[idx] = wr[((c0 + cc) * 9 + tap) * 512 + ocb * 32 + o];
        }
        for (int idx = t; idx < 3264; idx += 256) {
            int cc = idx / 408, rem = idx - cc * 408;
            int rr = rem / 68, xi = rem - rr * 68;
            int gy = y0 - 1 + rr, gx = xi - 1;
            float v = 0.f;
            if (gy >= 0 && gy < 64 && xi >= 1 && xi <= 64)
                v = x[((n * CIN + c0 + cc) * 64 + gy) * 64 + gx];
            in_s[idx] = v;
        }
        __syncthreads();
#pragma unroll 1
        for (int cc = 0; cc < 8; ++cc) {
            float sub[4][8];
#pragma unroll
            for (int i = 0; i < 4; i++)
#pragma unroll
                for (int j = 0; j < 8; j++) sub[i][j] = 0.f;
#pragma unroll
            for (int dy = 0; dy < 3; ++dy) {
                const float4* ip = (const float4*)&in_s[cc * 408 + (r + dy) * 68 + xo];
                float4 A = ip[0], B = ip[1], C4 = ip[2];
                float in12[12] = {A.x, A.y, A.z, A.w, B.x, B.y, B.z, B.w,
                                  C4.x, C4.y, C4.z, C4.w};
#pragma unroll
                for (int dx = 0; dx < 3; ++dx) {
                    const float4* wp =
                        (const float4*)&w_s[cc * 288 + (dy * 3 + dx) * 32 + tocg * 4];
                    float4 W0 = wp[0];
                    float w4[4] = {W0.x, W0.y, W0.z, W0.w};
#pragma unroll
                    for (int i = 0; i < 4; i++)
#pragma unroll
                        for (int j = 0; j < 8; j++)
                            sub[i][j] += w4[i] * in12[j + dx];
                }
            }
#pragma unroll
            for (int i = 0; i < 4; i++)
#pragma unroll
                for (int j = 0; j < 8; j++) accd[i][j] += (double)sub[i][j];
        }
        __syncthreads();
    }
    const int ocbase = ocb * 32 + tocg * 4;
#pragma unroll
    for (int i = 0; i < 4; i++) {
        double bb = (double)b1[ocbase + i];
#pragma unroll
        for (int j = 0; j < 8; j++) {
            double v = fmax(accd[i][j] + bb, 0.0);
            mid[((n * CIN + ocbase + i) * 64 + (y0 + r)) * 64 + xo + j] = (float)v;
        }
    }
}

// ---------------- fused 1x1 convs (36 loc + 18 score), f64 accumulation --------------
// also computes the f64 softmax fg score per anchor into fgbuf.
__global__ __launch_bounds__(256) void k_conv1(const float* __restrict__ mid,
                                               const float* __restrict__ wl,
                                               const float* __restrict__ bl,
                                               const float* __restrict__ wsc,
                                               const float* __restrict__ bs,
                                               float* __restrict__ out,
                                               double* __restrict__ fgbuf) {
    __shared__ float in_s[128 * 64];
    __shared__ float w_s[54 * 128];
    const int y = blockIdx.x;   // 64
    const int n = blockIdx.y;   // 8
    const int t = threadIdx.x;
    const int xx = t & 63, og = t >> 6;   // og uniform per wave
    double accd[14];
#pragma unroll
    for (int k = 0; k < 14; k++) accd[k] = 0.0;

    for (int c0 = 0; c0 < 512; c0 += 128) {
        for (int idx = t; idx < 128 * 64; idx += 256) {
            int cc = idx >> 6, x2 = idx & 63;
            in_s[idx] = mid[((n * CIN + c0 + cc) * 64 + y) * 64 + x2];
        }
        for (int idx = t; idx < 54 * 128; idx += 256) {
            int oc = idx >> 7, cc = idx & 127;
            w_s[idx] = (oc < 36) ? wl[oc * 512 + c0 + cc] : wsc[(oc - 36) * 512 + c0 + cc];
        }
        __syncthreads();
#pragma unroll 1
        for (int cc = 0; cc < 128; ++cc) {
            double iv = (double)in_s[cc * 64 + xx];
#pragma unroll
            for (int k = 0; k < 14; k++) {
                int oc = og * 14 + k;
                if (oc < 54) accd[k] += (double)w_s[oc * 128 + cc] * iv;
            }
        }
        __syncthreads();
    }
    const int pos = y * 64 + xx;
    double sv[14];
#pragma unroll
    for (int k = 0; k < 14; k++) {
        int oc = og * 14 + k;
        if (oc >= 54) break;
        if (oc < 36) {
            double v = accd[k] + (double)bl[oc];
            int a = oc >> 2, cd = oc & 3;
            out[O_LOCS + ((size_t)(n * NA + pos * 9 + a)) * 4 + cd] = (float)v;
        } else {
            sv[k] = accd[k] + (double)bs[oc - 36];
            int c2 = oc - 36, a = c2 >> 1, cls = c2 & 1;
            out[O_SCORES + ((size_t)(n * NA + pos * 9 + a)) * 2 + cls] = (float)sv[k];
        }
    }
#pragma unroll
    for (int k = 0; k < 13; k++) {
        int oc = og * 14 + k;
        if (oc >= 36 && oc < 54 && ((oc - 36) & 1) == 0) {
            double s0 = sv[k], s1 = sv[k + 1];
            double m = fmax(s0, s1);
            double e0 = exp(s0 - m), e1 = exp(s1 - m);
            double fg = e1 / (e0 + e1);
            int a = (oc - 36) >> 1;
            fgbuf[(size_t)n * NA + pos * 9 + a] = fg;
        }
    }
}

// ---------------- keys: mono64(f64 fg) with low 16 bits = inverted index -------------
__global__ __launch_bounds__(256) void k_keys(const float* __restrict__ out,
                                              const double* __restrict__ fgbuf,
                                              unsigned long long* __restrict__ keys) {
    const int n = blockIdx.x / 144;
    const int i = (blockIdx.x % 144) * 256 + threadIdx.x;
    int pos = i / 9, a = i - pos * 9;
    float anc[4]; anchor_for(a, pos, anc);
    float4 L = *(const float4*)&out[O_LOCS + (size_t)(n * NA + i) * 4];
    float box[4];
    bool ok = decode_box(L, anc, box);
    double f = ok ? fgbuf[(size_t)n * NA + i] : (double)NEGV;
    unsigned long long m = mono64(f);
    keys[(size_t)n * NA + i] =
        (m & 0xFFFFFFFFFFFF0000ull) | (unsigned long long)(0xFFFFu - (unsigned)i);
}

// ---------------- exact 64-bit radix select: kth[n] = 6000th largest key -------------
// 5 levels: 13+13+13+13+12 bits. Keys unique -> count(key >= kth) == 6000 exactly.
__global__ __launch_bounds__(256) void k_select(const unsigned long long* __restrict__ keys,
                                                unsigned long long* __restrict__ kth) {
    __shared__ unsigned int hist[8192];
    __shared__ unsigned int gs[256];
    __shared__ unsigned long long s_pref;
    __shared__ int s_plen, s_rem;
    const int n = blockIdx.x, t = threadIdx.x;
    if (t == 0) { s_pref = 0ull; s_plen = 0; s_rem = NPRE; }
    __syncthreads();
    const int shifts[5] = {51, 38, 25, 12, 0};
    const int widths[5] = {13, 13, 13, 13, 12};
    for (int lev = 0; lev < 5; ++lev) {
        const int nb = 1 << widths[lev];
        for (int b = t; b < nb; b += 256) hist[b] = 0;
        __syncthreads();
        const unsigned long long pref = s_pref;
        const int plen = s_plen;
        for (int i = t; i < NA; i += 256) {
            unsigned long long key = keys[(size_t)n * NA + i];
            if (plen == 0 || (key >> (64 - plen)) == pref) {
                unsigned int bin = (unsigned int)((key >> shifts[lev]) & (unsigned)(nb - 1));
                atomicAdd(&hist[bin], 1u);
            }
        }
        __syncthreads();
        const int gsz = nb >> 8;   // bins per thread-group
        unsigned int s = 0;
        for (int m = 0; m < gsz; m++) s += hist[t * gsz + m];
        gs[t] = s;
        __syncthreads();
        if (t == 0) {
            const unsigned int rem = (unsigned int)s_rem;
            unsigned int acc = 0; int selbin = 0;
            for (int g = 255; g >= 0; --g) {
                if (acc + gs[g] >= rem) {
                    for (int b = g * gsz + gsz - 1; b >= g * gsz; --b) {
                        if (acc + hist[b] >= rem) { selbin = b; break; }
                        acc += hist[b];
                    }
                    break;
                }
                acc += gs[g];
            }
            s_rem = (int)(rem - acc);
            s_pref = (s_pref << widths[lev]) | (unsigned long long)(unsigned)selbin;
            s_plen += widths[lev];
        }
        __syncthreads();
    }
    if (t == 0) kth[n] = s_pref;
}

// ---------------- compact: exactly the 6000 keys >= kth ------------------------------
__global__ void k_compact(const unsigned long long* __restrict__ keys,
                          const unsigned long long* __restrict__ kth,
                          unsigned long long* __restrict__ cbuf,
                          unsigned int* __restrict__ cnt) {
    const int n = blockIdx.x / 144;
    const int i = (blockIdx.x % 144) * 256 + threadIdx.x;
    unsigned long long key = keys[(size_t)n * NA + i];
    if (key >= kth[n]) {
        unsigned int p = atomicAdd(&cnt[n], 1u);
        if (p < CBUF_CAP) cbuf[(size_t)n * CBUF_CAP + p] = key;
    }
}

// ---------------- per-image LDS bitonic sort (descending), emit top-6000 boxes -------
__global__ __launch_bounds__(256) void k_sort(const unsigned long long* __restrict__ cbuf,
                                              const float* __restrict__ out,
                                              float* __restrict__ bsort,
                                              unsigned char* __restrict__ vflag) {
    __shared__ unsigned long long arr[CBUF_CAP];
    const int n = blockIdx.x, t = threadIdx.x;
    for (int idx = t; idx < CBUF_CAP; idx += 256)
        arr[idx] = (idx < NPRE) ? cbuf[(size_t)n * CBUF_CAP + idx] : 0ull;
    __syncthreads();
    for (int k = 2; k <= CBUF_CAP; k <<= 1)
        for (int j = k >> 1; j > 0; j >>= 1) {
            for (int i = t; i < CBUF_CAP; i += 256) {
                int ixj = i ^ j;
                if (ixj > i) {
                    unsigned long long a = arr[i], b = arr[ixj];
                    bool up = (i & k) == 0;
                    if (up ? (a < b) : (a > b)) { arr[i] = b; arr[ixj] = a; }
                }
            }
            __syncthreads();
        }
    for (int r = t; r < NPRE; r += 256) {
        unsigned long long key = arr[r];
        unsigned int i = 0xFFFFu - (unsigned int)(key & 0xFFFFull);
        int pos = i / 9, a = i - pos * 9;
        float anc[4]; anchor_for(a, pos, anc);
        float4 L = *(const float4*)&out[O_LOCS + (size_t)(n * NA + i) * 4];
        float box[4];
        bool ok = decode_box(L, anc, box);
        ((float4*)bsort)[(size_t)n * NPRE + r] = make_float4(box[0], box[1], box[2], box[3]);
        vflag[(size_t)n * NPRE + r] = ok ? 1 : 0;
    }
}

// ---------------- suppression bitmask matrix (bits j>i with IoU>0.7) -----------------
__global__ __launch_bounds__(256) void k_mask(const float* __restrict__ bsort,
                                              unsigned long long* __restrict__ masks) {
    __shared__ float4 bx[1024];
    const int n = blockIdx.y;
    const int i = blockIdx.x * 256 + threadIdx.x;
    const bool have = i < NPRE;
    float4 bi = make_float4(0, 0, 0, 0); float areai = 0.f;
    if (have) {
        bi = ((const float4*)bsort)[(size_t)n * NPRE + i];
        areai = fmulr(fsubr(bi.z, bi.x), fsubr(bi.w, bi.y));
    }
    for (int jc = 0; jc < 6; ++jc) {
        int jn = min(1024, NPRE - jc * 1024);
        __syncthreads();
        for (int jj = threadIdx.x; jj < jn; jj += 256)
            bx[jj] = ((const float4*)bsort)[(size_t)n * NPRE + jc * 1024 + jj];
        __syncthreads();
        for (int w = 0; w < 16; ++w) {
            int gw = jc * 16 + w;
            if (gw >= NWORD) break;
            unsigned long long m = 0ull;
            int jbase = jc * 1024 + w * 64;
            if (have && jbase + 63 > i) {
#pragma unroll 1
                for (int b = 0; b < 64; b++) {
                    int j = jbase + b;
                    if (j > i && j < NPRE) {
                        float4 bj = bx[w * 64 + b];
                        float ih = fmaxf(fsubr(fminf(bi.z, bj.z), fmaxf(bi.x, bj.x)), 0.f);
                        float iw = fmaxf(fsubr(fminf(bi.w, bj.w), fmaxf(bi.y, bj.y)), 0.f);
                        float inter = fmulr(ih, iw);
                        float areaj = fmulr(fsubr(bj.z, bj.x), fsubr(bj.w, bj.y));
                        float den = faddr(fsubr(faddr(areai, areaj), inter), 1e-9f);
                        float iou = __fdiv_rn(inter, den);
                        if (iou > 0.7f) m |= (1ull << b);
                    }
                }
            }
            if (have) masks[((size_t)n * NPRE + i) * NWORD + gw] = m;
        }
    }
}

// ---------------- serial greedy scan with early exit at 300 kept ---------------------
__global__ __launch_bounds__(128) void k_scan(const unsigned long long* __restrict__ masks,
                                              const unsigned char* __restrict__ vflag,
                                              const float* __restrict__ bsort,
                                              float* __restrict__ out) {
    __shared__ unsigned long long sup[NWORD];
    __shared__ unsigned long long valw[NWORD];
    __shared__ int kept;
    const int n = blockIdx.x, t = threadIdx.x;
    if (t == 0) kept = 0;
    if (t < NWORD) {
        sup[t] = 0ull;
        unsigned long long v = 0ull;
        for (int b = 0; b < 64; b++) {
            int r = t * 64 + b;
            if (r < NPRE && vflag[(size_t)n * NPRE + r]) v |= (1ull << b);
        }
        valw[t] = v;
    }
    __syncthreads();
    for (int i = 0; i < NPRE; ++i) {
        bool keep = ((valw[i >> 6] >> (i & 63)) & 1ull) && !((sup[i >> 6] >> (i & 63)) & 1ull);
        if (keep) {
            if (t < NWORD) sup[t] |= masks[((size_t)n * NPRE + i) * NWORD + t];
            if (t == 0) {
                int r = kept;
                if (r < NPOST) {
                    float4 b4 = ((const float4*)bsort)[(size_t)n * NPRE + i];
                    out[O_ROIS + (size_t)(n * NPOST + r) * 4 + 0] = b4.x;
                    out[O_ROIS + (size_t)(n * NPOST + r) * 4 + 1] = b4.y;
                    out[O_ROIS + (size_t)(n * NPOST + r) * 4 + 2] = b4.z;
                    out[O_ROIS + (size_t)(n * NPOST + r) * 4 + 3] = b4.w;
                    out[O_RIDX + n * NPOST + r] = (float)n;
                }
                kept = r + 1;
            }
            __syncthreads();
            if (kept >= NPOST) break;
        }
    }
    __syncthreads();
    for (int r = kept + t; r < NPOST; r += 128) {
        out[O_ROIS + (size_t)(n * NPOST + r) * 4 + 0] = 0.f;
        out[O_ROIS + (size_t)(n * NPOST + r) * 4 + 1] = 0.f;
        out[O_ROIS + (size_t)(n * NPOST + r) * 4 + 2] = 0.f;
        out[O_ROIS + (size_t)(n * NPOST + r) * 4 + 3] = 0.f;
        out[O_RIDX + n * NPOST + r] = -1.0f;
    }
}

// ---------------- anchors output ------------------------------------------------------
__global__ void k_anchor(float* __restrict__ out) {
    int i = blockIdx.x * 256 + threadIdx.x;
    if (i >= NA) return;
    int pos = i / 9, a = i - pos * 9;
    float anc[4]; anchor_for(a, pos, anc);
    out[O_ANCH + (size_t)i * 4 + 0] = anc[0];
    out[O_ANCH + (size_t)i * 4 + 1] = anc[1];
    out[O_ANCH + (size_t)i * 4 + 2] = anc[2];
    out[O_ANCH + (size_t)i * 4 + 3] = anc[3];
}

extern "C" void kernel_launch(void* const* d_in, const int* in_sizes, int n_in,
                              void* d_out, int out_size, void* d_ws, size_t ws_size,
                              hipStream_t stream) {
    const float* x   = (const float*)d_in[0];
    const float* w1  = (const float*)d_in[1];
    const float* b1  = (const float*)d_in[2];
    const float* wsc = (const float*)d_in[3];
    const float* bsc = (const float*)d_in[4];
    const float* wlc = (const float*)d_in[5];
    const float* blc = (const float*)d_in[6];
    float* out = (float*)d_out;
    char* ws = (char*)d_ws;

    float* wr                 = (float*)(ws + 0);                       //  9,437,184
    float* mid                = (float*)(ws + 9437184);                 // 67,108,864
    double* fgbuf             = (double*)(ws + 76546048);               //  2,359,296
    unsigned long long* keys  = (unsigned long long*)(ws + 78905344);   //  2,359,296
    unsigned long long* kth   = (unsigned long long*)(ws + 81264640);   //        64 (pad 512)
    unsigned int* cnt         = (unsigned int*)(ws + 81265152);         //        32 (pad 512)
    unsigned long long* cbuf  = (unsigned long long*)(ws + 81265664);   //    524,288
    float* bsort              = (float*)(ws + 81789952);                //    768,000
    unsigned char* vflag      = (unsigned char*)(ws + 82557952);        //     48,128
    unsigned long long* masks = (unsigned long long*)(ws + 82606080);   // 36,096,000 -> ~118.7MB

    hipMemsetAsync(cnt, 0, 8 * 4, stream);

    k_wreord<<<(512 * 9 * 512 + 255) / 256, 256, 0, stream>>>(w1, wr);
    dim3 g3(16, 16, 8);
    k_conv3<<<g3, 256, 0, stream>>>(x, wr, b1, mid);
    dim3 g1(64, 8);
    k_conv1<<<g1, 256, 0, stream>>>(mid, wlc, blc, wsc, bsc, out, fgbuf);
    k_keys<<<1152, 256, 0, stream>>>(out, fgbuf, keys);
    k_select<<<8, 256, 0, stream>>>(keys, kth);
    k_compact<<<1152, 256, 0, stream>>>(keys, kth, cbuf, cnt);
    k_sort<<<8, 256, 0, stream>>>(cbuf, out, bsort, vflag);
    dim3 gm(24, 8);
    k_mask<<<gm, 256, 0, stream>>>(bsort, masks);
    k_scan<<<8, 128, 0, stream>>>(masks, vflag, bsort, out);
    k_anchor<<<144, 256, 0, stream>>>(out);
}

// Round 4
// 4842.017 us; speedup vs baseline: 1.1163x; 1.1163x over previous
//
#include <hip/hip_runtime.h>
#include <cstdint>
#include <cstddef>

#define CIN 512
#define NA 36864           // 4096 positions * 9 anchors
#define NPRE 6000
#define NPOST 300
#define CBUF_CAP 8192
#define NWORD 94           // ceil(6000/64)
#define NEGV -1000000000.0f

// d_out float offsets (return-order concat)
#define O_LOCS   0
#define O_SCORES 1179648   // 8*36864*4
#define O_ROIS   1769472   // + 8*36864*2
#define O_RIDX   1779072   // + 8*300*4
#define O_ANCH   1781472   // + 8*300

// ---------- exact-rounding helpers (prevent FMA contraction where order matters) ----
__device__ __forceinline__ float fmulr(float a, float b) { return __fmul_rn(a, b); }
__device__ __forceinline__ float faddr(float a, float b) { return __fadd_rn(a, b); }
__device__ __forceinline__ float fsubr(float a, float b) { return __fsub_rn(a, b); }

__device__ __forceinline__ void anchor_for(int a, int pos, float* anc) {
    const double rat[3] = {0.5, 1.0, 2.0};
    const double scl[3] = {8.0, 16.0, 32.0};
    int ri = a / 3, si = a - ri * 3;
    double h = 16.0 * scl[si] * sqrt(rat[ri]);
    double w = 16.0 * scl[si] * sqrt(1.0 / rat[ri]);
    float a0 = (float)(8.0 - h * 0.5);
    float a1 = (float)(8.0 - w * 0.5);
    float a2 = (float)(8.0 + h * 0.5);
    float a3 = (float)(8.0 + w * 0.5);
    int y = pos >> 6, x = pos & 63;
    float sy = (float)(y * 16), sx = (float)(x * 16);
    anc[0] = faddr(a0, sy); anc[1] = faddr(a1, sx);
    anc[2] = faddr(a2, sy); anc[3] = faddr(a3, sx);
}

__device__ __forceinline__ bool decode_box(float4 L, const float* anc, float* box) {
    float ah  = fsubr(anc[2], anc[0]);
    float aw  = fsubr(anc[3], anc[1]);
    float acy = faddr(anc[0], fmulr(0.5f, ah));
    float acx = faddr(anc[1], fmulr(0.5f, aw));
    float cy  = faddr(fmulr(L.x, ah), acy);
    float cx  = faddr(fmulr(L.y, aw), acx);
    float h   = fmulr(ah, expf(L.z));
    float w   = fmulr(aw, expf(L.w));
    float y1 = fminf(fmaxf(fsubr(cy, fmulr(0.5f, h)), 0.0f), 1024.0f);
    float x1 = fminf(fmaxf(fsubr(cx, fmulr(0.5f, w)), 0.0f), 1024.0f);
    float y2 = fminf(fmaxf(faddr(cy, fmulr(0.5f, h)), 0.0f), 1024.0f);
    float x2 = fminf(fmaxf(faddr(cx, fmulr(0.5f, w)), 0.0f), 1024.0f);
    box[0] = y1; box[1] = x1; box[2] = y2; box[3] = x2;
    float hs = fsubr(y2, y1), ws2 = fsubr(x2, x1);
    return (hs >= 16.0f) && (ws2 >= 16.0f);
}

// monotonic 64-bit map of a double (totally ordered, sign handled)
__device__ __forceinline__ unsigned long long mono64(double f) {
    unsigned long long u = (unsigned long long)__double_as_longlong(f);
    return (u & 0x8000000000000000ull) ? ~u : (u | 0x8000000000000000ull);
}

// ---------------- weight reorder: w1[oc][c][ky][kx] -> wr[(c*9+tap)*512+oc] ----------
// LDS-tiled transpose: coalesced reads AND writes.
__global__ __launch_bounds__(256) void k_wreord(const float* __restrict__ w1,
                                                float* __restrict__ wr) {
    __shared__ float tile[32][65];
    const int ct0 = blockIdx.x * 64;   // 72 tiles over 4608 (c*9+tap)
    const int oc0 = blockIdx.y * 32;   // 16 tiles over 512
    const int t = threadIdx.x;
    for (int i = t; i < 32 * 64; i += 256) {
        int r = i >> 6, c = i & 63;
        tile[r][c] = w1[(size_t)(oc0 + r) * 4608 + ct0 + c];
    }
    __syncthreads();
    for (int i = t; i < 32 * 64; i += 256) {
        int cl = i >> 5, ol = i & 31;
        wr[(size_t)(ct0 + cl) * 512 + oc0 + ol] = tile[ol][cl];
    }
}

// ---------------- 3x3 conv 512->512 + bias + relu, f64 main accumulators -------------
// block: 32 oc x 4 rows x 64 cols, 256 threads; per-thread 4 oc x 8 cols.
// fp32 sub-accumulate over 2 input channels (18 taps) merged into f64 (VGPR-resident
// via launch_bounds cap) -> conv error ~6e-8, fg-ordering error ~4e-9 << rank gaps.
__global__ __launch_bounds__(256, 2) void k_conv3(const float* __restrict__ x,
                                                  const float* __restrict__ wr,
                                                  const float* __restrict__ b1,
                                                  float* __restrict__ mid) {
    __shared__ float in_s[8 * 6 * 68];   // [cc][rr(6)][xi(68)]  13056 floats
    __shared__ float w_s[8 * 9 * 32];    // [cc][tap][oc32]       2304 floats
    const int yb  = blockIdx.x;          // 16
    const int ocb = blockIdx.y;          // 16
    const int n   = blockIdx.z;          // 8
    const int t   = threadIdx.x;
    const int y0  = yb * 4;
    const int tocg = t >> 5;             // 0..7 -> oc group of 4
    const int tx   = t & 31;
    const int r    = tx >> 3;            // 0..3 row
    const int xo   = (tx & 7) << 3;      // 0..56 col octet

    double accd[4][8];
#pragma unroll
    for (int i = 0; i < 4; i++)
#pragma unroll
        for (int j = 0; j < 8; j++) accd[i][j] = 0.0;

    for (int ch = 0; ch < 64; ++ch) {
        const int c0 = ch * 8;
        for (int idx = t; idx < 2304; idx += 256) {
            int cc = idx / 288, rem = idx - cc * 288;
            int tap = rem >> 5, o = rem & 31;
            w_s[idx] = wr[((c0 + cc) * 9 + tap) * 512 + ocb * 32 + o];
        }
        for (int idx = t; idx < 3264; idx += 256) {
            int cc = idx / 408, rem = idx - cc * 408;
            int rr = rem / 68, xi = rem - rr * 68;
            int gy = y0 - 1 + rr, gx = xi - 1;
            float v = 0.f;
            if (gy >= 0 && gy < 64 && xi >= 1 && xi <= 64)
                v = x[((n * CIN + c0 + cc) * 64 + gy) * 64 + gx];
            in_s[idx] = v;
        }
        __syncthreads();
#pragma unroll 1
        for (int ccp = 0; ccp < 4; ++ccp) {
            float sub[4][8];
#pragma unroll
            for (int i = 0; i < 4; i++)
#pragma unroll
                for (int j = 0; j < 8; j++) sub[i][j] = 0.f;
#pragma unroll
            for (int cc2 = 0; cc2 < 2; ++cc2) {
                const int cc = ccp * 2 + cc2;
#pragma unroll
                for (int dy = 0; dy < 3; ++dy) {
                    const float4* ip = (const float4*)&in_s[cc * 408 + (r + dy) * 68 + xo];
                    float4 A = ip[0], B = ip[1], C4 = ip[2];
                    float in12[12] = {A.x, A.y, A.z, A.w, B.x, B.y, B.z, B.w,
                                      C4.x, C4.y, C4.z, C4.w};
#pragma unroll
                    for (int dx = 0; dx < 3; ++dx) {
                        const float4* wp =
                            (const float4*)&w_s[cc * 288 + (dy * 3 + dx) * 32 + tocg * 4];
                        float4 W0 = wp[0];
                        float w4[4] = {W0.x, W0.y, W0.z, W0.w};
#pragma unroll
                        for (int i = 0; i < 4; i++)
#pragma unroll
                            for (int j = 0; j < 8; j++)
                                sub[i][j] += w4[i] * in12[j + dx];
                    }
                }
            }
#pragma unroll
            for (int i = 0; i < 4; i++)
#pragma unroll
                for (int j = 0; j < 8; j++) accd[i][j] += (double)sub[i][j];
        }
        __syncthreads();
    }
    const int ocbase = ocb * 32 + tocg * 4;
#pragma unroll
    for (int i = 0; i < 4; i++) {
        double bb = (double)b1[ocbase + i];
#pragma unroll
        for (int j = 0; j < 8; j++) {
            double v = fmax(accd[i][j] + bb, 0.0);
            mid[((n * CIN + ocbase + i) * 64 + (y0 + r)) * 64 + xo + j] = (float)v;
        }
    }
}

// ---------------- fused 1x1 convs (36 loc + 18 score), f64 accumulation --------------
// also computes the f64 softmax fg score per anchor into fgbuf.
__global__ __launch_bounds__(256) void k_conv1(const float* __restrict__ mid,
                                               const float* __restrict__ wl,
                                               const float* __restrict__ bl,
                                               const float* __restrict__ wsc,
                                               const float* __restrict__ bs,
                                               float* __restrict__ out,
                                               double* __restrict__ fgbuf) {
    __shared__ float in_s[128 * 64];
    __shared__ float w_s[54 * 128];
    const int y = blockIdx.x;   // 64
    const int n = blockIdx.y;   // 8
    const int t = threadIdx.x;
    const int xx = t & 63, og = t >> 6;   // og uniform per wave
    double accd[14];
#pragma unroll
    for (int k = 0; k < 14; k++) accd[k] = 0.0;

    for (int c0 = 0; c0 < 512; c0 += 128) {
        for (int idx = t; idx < 128 * 64; idx += 256) {
            int cc = idx >> 6, x2 = idx & 63;
            in_s[idx] = mid[((n * CIN + c0 + cc) * 64 + y) * 64 + x2];
        }
        for (int idx = t; idx < 54 * 128; idx += 256) {
            int oc = idx >> 7, cc = idx & 127;
            w_s[idx] = (oc < 36) ? wl[oc * 512 + c0 + cc] : wsc[(oc - 36) * 512 + c0 + cc];
        }
        __syncthreads();
#pragma unroll 1
        for (int cc = 0; cc < 128; ++cc) {
            double iv = (double)in_s[cc * 64 + xx];
#pragma unroll
            for (int k = 0; k < 14; k++) {
                int oc = og * 14 + k;
                if (oc < 54) accd[k] += (double)w_s[oc * 128 + cc] * iv;
            }
        }
        __syncthreads();
    }
    const int pos = y * 64 + xx;
    double sv[14];
#pragma unroll
    for (int k = 0; k < 14; k++) {
        int oc = og * 14 + k;
        if (oc >= 54) break;
        if (oc < 36) {
            double v = accd[k] + (double)bl[oc];
            int a = oc >> 2, cd = oc & 3;
            out[O_LOCS + ((size_t)(n * NA + pos * 9 + a)) * 4 + cd] = (float)v;
        } else {
            sv[k] = accd[k] + (double)bs[oc - 36];
            int c2 = oc - 36, a = c2 >> 1, cls = c2 & 1;
            out[O_SCORES + ((size_t)(n * NA + pos * 9 + a)) * 2 + cls] = (float)sv[k];
        }
    }
#pragma unroll
    for (int k = 0; k < 13; k++) {
        int oc = og * 14 + k;
        if (oc >= 36 && oc < 54 && ((oc - 36) & 1) == 0) {
            double s0 = sv[k], s1 = sv[k + 1];
            double m = fmax(s0, s1);
            double e0 = exp(s0 - m), e1 = exp(s1 - m);
            double fg = e1 / (e0 + e1);
            int a = (oc - 36) >> 1;
            fgbuf[(size_t)n * NA + pos * 9 + a] = fg;
        }
    }
}

// ---------------- keys: mono64(f64 fg) with low 16 bits = inverted index -------------
__global__ __launch_bounds__(256) void k_keys(const float* __restrict__ out,
                                              const double* __restrict__ fgbuf,
                                              unsigned long long* __restrict__ keys) {
    const int n = blockIdx.x / 144;
    const int i = (blockIdx.x % 144) * 256 + threadIdx.x;
    int pos = i / 9, a = i - pos * 9;
    float anc[4]; anchor_for(a, pos, anc);
    float4 L = *(const float4*)&out[O_LOCS + (size_t)(n * NA + i) * 4];
    float box[4];
    bool ok = decode_box(L, anc, box);
    double f = ok ? fgbuf[(size_t)n * NA + i] : (double)NEGV;
    unsigned long long m = mono64(f);
    keys[(size_t)n * NA + i] =
        (m & 0xFFFFFFFFFFFF0000ull) | (unsigned long long)(0xFFFFu - (unsigned)i);
}

// ---------------- exact 64-bit radix select: kth[n] = 6000th largest key -------------
// 5 levels: 13+13+13+13+12 bits. Keys unique -> count(key >= kth) == 6000 exactly.
__global__ __launch_bounds__(1024) void k_select(const unsigned long long* __restrict__ keys,
                                                 unsigned long long* __restrict__ kth) {
    __shared__ unsigned int hist[8192];
    __shared__ unsigned int gs[256];
    __shared__ unsigned long long s_pref;
    __shared__ int s_plen, s_rem;
    const int n = blockIdx.x, t = threadIdx.x;
    if (t == 0) { s_pref = 0ull; s_plen = 0; s_rem = NPRE; }
    __syncthreads();
    const int shifts[5] = {51, 38, 25, 12, 0};
    const int widths[5] = {13, 13, 13, 13, 12};
    for (int lev = 0; lev < 5; ++lev) {
        const int nb = 1 << widths[lev];
        for (int b = t; b < nb; b += 1024) hist[b] = 0;
        __syncthreads();
        const unsigned long long pref = s_pref;
        const int plen = s_plen;
        for (int i = t; i < NA; i += 1024) {
            unsigned long long key = keys[(size_t)n * NA + i];
            if (plen == 0 || (key >> (64 - plen)) == pref) {
                unsigned int bin = (unsigned int)((key >> shifts[lev]) & (unsigned)(nb - 1));
                atomicAdd(&hist[bin], 1u);
            }
        }
        __syncthreads();
        const int gsz = nb >> 8;   // bins per thread-group
        if (t < 256) {
            unsigned int s = 0;
            for (int m = 0; m < gsz; m++) s += hist[t * gsz + m];
            gs[t] = s;
        }
        __syncthreads();
        if (t == 0) {
            const unsigned int rem = (unsigned int)s_rem;
            unsigned int acc = 0; int selbin = 0;
            for (int g = 255; g >= 0; --g) {
                if (acc + gs[g] >= rem) {
                    for (int b = g * gsz + gsz - 1; b >= g * gsz; --b) {
                        if (acc + hist[b] >= rem) { selbin = b; break; }
                        acc += hist[b];
                    }
                    break;
                }
                acc += gs[g];
            }
            s_rem = (int)(rem - acc);
            s_pref = (s_pref << widths[lev]) | (unsigned long long)(unsigned)selbin;
            s_plen += widths[lev];
        }
        __syncthreads();
    }
    if (t == 0) kth[n] = s_pref;
}

// ---------------- compact: exactly the 6000 keys >= kth ------------------------------
__global__ void k_compact(const unsigned long long* __restrict__ keys,
                          const unsigned long long* __restrict__ kth,
                          unsigned long long* __restrict__ cbuf,
                          unsigned int* __restrict__ cnt) {
    const int n = blockIdx.x / 144;
    const int i = (blockIdx.x % 144) * 256 + threadIdx.x;
    unsigned long long key = keys[(size_t)n * NA + i];
    if (key >= kth[n]) {
        unsigned int p = atomicAdd(&cnt[n], 1u);
        if (p < CBUF_CAP) cbuf[(size_t)n * CBUF_CAP + p] = key;
    }
}

// ---------------- per-image LDS bitonic sort (descending), emit top-6000 boxes -------
__global__ __launch_bounds__(1024) void k_sort(const unsigned long long* __restrict__ cbuf,
                                               const float* __restrict__ out,
                                               float* __restrict__ bsort,
                                               unsigned char* __restrict__ vflag) {
    __shared__ unsigned long long arr[CBUF_CAP];
    const int n = blockIdx.x, t = threadIdx.x;
    for (int idx = t; idx < CBUF_CAP; idx += 1024)
        arr[idx] = (idx < NPRE) ? cbuf[(size_t)n * CBUF_CAP + idx] : 0ull;
    __syncthreads();
    for (int k = 2; k <= CBUF_CAP; k <<= 1)
        for (int j = k >> 1; j > 0; j >>= 1) {
            for (int i = t; i < CBUF_CAP; i += 1024) {
                int ixj = i ^ j;
                if (ixj > i) {
                    unsigned long long a = arr[i], b = arr[ixj];
                    bool up = (i & k) == 0;
                    if (up ? (a < b) : (a > b)) { arr[i] = b; arr[ixj] = a; }
                }
            }
            __syncthreads();
        }
    for (int r = t; r < NPRE; r += 1024) {
        unsigned long long key = arr[r];
        unsigned int i = 0xFFFFu - (unsigned int)(key & 0xFFFFull);
        int pos = i / 9, a = i - pos * 9;
        float anc[4]; anchor_for(a, pos, anc);
        float4 L = *(const float4*)&out[O_LOCS + (size_t)(n * NA + i) * 4];
        float box[4];
        bool ok = decode_box(L, anc, box);
        ((float4*)bsort)[(size_t)n * NPRE + r] = make_float4(box[0], box[1], box[2], box[3]);
        vflag[(size_t)n * NPRE + r] = ok ? 1 : 0;
    }
}

// ---------------- suppression bitmask matrix (bits j>i with IoU>0.7) -----------------
__global__ __launch_bounds__(256) void k_mask(const float* __restrict__ bsort,
                                              unsigned long long* __restrict__ masks) {
    __shared__ float4 bx[1024];
    const int n = blockIdx.y;
    const int i = blockIdx.x * 256 + threadIdx.x;
    const bool have = i < NPRE;
    float4 bi = make_float4(0, 0, 0, 0); float areai = 0.f;
    if (have) {
        bi = ((const float4*)bsort)[(size_t)n * NPRE + i];
        areai = fmulr(fsubr(bi.z, bi.x), fsubr(bi.w, bi.y));
    }
    for (int jc = 0; jc < 6; ++jc) {
        int jn = min(1024, NPRE - jc * 1024);
        __syncthreads();
        for (int jj = threadIdx.x; jj < jn; jj += 256)
            bx[jj] = ((const float4*)bsort)[(size_t)n * NPRE + jc * 1024 + jj];
        __syncthreads();
        for (int w = 0; w < 16; ++w) {
            int gw = jc * 16 + w;
            if (gw >= NWORD) break;
            unsigned long long m = 0ull;
            int jbase = jc * 1024 + w * 64;
            if (have && jbase + 63 > i) {
#pragma unroll 1
                for (int b = 0; b < 64; b++) {
                    int j = jbase + b;
                    if (j > i && j < NPRE) {
                        float4 bj = bx[w * 64 + b];
                        float ih = fmaxf(fsubr(fminf(bi.z, bj.z), fmaxf(bi.x, bj.x)), 0.f);
                        float iw = fmaxf(fsubr(fminf(bi.w, bj.w), fmaxf(bi.y, bj.y)), 0.f);
                        float inter = fmulr(ih, iw);
                        float areaj = fmulr(fsubr(bj.z, bj.x), fsubr(bj.w, bj.y));
                        float den = faddr(fsubr(faddr(areai, areaj), inter), 1e-9f);
                        float iou = __fdiv_rn(inter, den);
                        if (iou > 0.7f) m |= (1ull << b);
                    }
                }
            }
            if (have) masks[((size_t)n * NPRE + i) * NWORD + gw] = m;
        }
    }
}

// ---------------- serial greedy scan with early exit at 300 kept ---------------------
__global__ __launch_bounds__(128) void k_scan(const unsigned long long* __restrict__ masks,
                                              const unsigned char* __restrict__ vflag,
                                              const float* __restrict__ bsort,
                                              float* __restrict__ out) {
    __shared__ unsigned long long sup[NWORD];
    __shared__ unsigned long long valw[NWORD];
    __shared__ int kept;
    const int n = blockIdx.x, t = threadIdx.x;
    if (t == 0) kept = 0;
    if (t < NWORD) {
        sup[t] = 0ull;
        unsigned long long v = 0ull;
        for (int b = 0; b < 64; b++) {
            int r = t * 64 + b;
            if (r < NPRE && vflag[(size_t)n * NPRE + r]) v |= (1ull << b);
        }
        valw[t] = v;
    }
    __syncthreads();
    for (int i = 0; i < NPRE; ++i) {
        bool keep = ((valw[i >> 6] >> (i & 63)) & 1ull) && !((sup[i >> 6] >> (i & 63)) & 1ull);
        if (keep) {
            if (t < NWORD) sup[t] |= masks[((size_t)n * NPRE + i) * NWORD + t];
            if (t == 0) {
                int r = kept;
                if (r < NPOST) {
                    float4 b4 = ((const float4*)bsort)[(size_t)n * NPRE + i];
                    out[O_ROIS + (size_t)(n * NPOST + r) * 4 + 0] = b4.x;
                    out[O_ROIS + (size_t)(n * NPOST + r) * 4 + 1] = b4.y;
                    out[O_ROIS + (size_t)(n * NPOST + r) * 4 + 2] = b4.z;
                    out[O_ROIS + (size_t)(n * NPOST + r) * 4 + 3] = b4.w;
                    out[O_RIDX + n * NPOST + r] = (float)n;
                }
                kept = r + 1;
            }
            __syncthreads();
            if (kept >= NPOST) break;
        }
    }
    __syncthreads();
    for (int r = kept + t; r < NPOST; r += 128) {
        out[O_ROIS + (size_t)(n * NPOST + r) * 4 + 0] = 0.f;
        out[O_ROIS + (size_t)(n * NPOST + r) * 4 + 1] = 0.f;
        out[O_ROIS + (size_t)(n * NPOST + r) * 4 + 2] = 0.f;
        out[O_ROIS + (size_t)(n * NPOST + r) * 4 + 3] = 0.f;
        out[O_RIDX + n * NPOST + r] = -1.0f;
    }
}

// ---------------- anchors output ------------------------------------------------------
__global__ void k_anchor(float* __restrict__ out) {
    int i = blockIdx.x * 256 + threadIdx.x;
    if (i >= NA) return;
    int pos = i / 9, a = i - pos * 9;
    float anc[4]; anchor_for(a, pos, anc);
    out[O_ANCH + (size_t)i * 4 + 0] = anc[0];
    out[O_ANCH + (size_t)i * 4 + 1] = anc[1];
    out[O_ANCH + (size_t)i * 4 + 2] = anc[2];
    out[O_ANCH + (size_t)i * 4 + 3] = anc[3];
}

extern "C" void kernel_launch(void* const* d_in, const int* in_sizes, int n_in,
                              void* d_out, int out_size, void* d_ws, size_t ws_size,
                              hipStream_t stream) {
    const float* x   = (const float*)d_in[0];
    const float* w1  = (const float*)d_in[1];
    const float* b1  = (const float*)d_in[2];
    const float* wsc = (const float*)d_in[3];
    const float* bsc = (const float*)d_in[4];
    const float* wlc = (const float*)d_in[5];
    const float* blc = (const float*)d_in[6];
    float* out = (float*)d_out;
    char* ws = (char*)d_ws;

    float* wr                 = (float*)(ws + 0);                       //  9,437,184
    float* mid                = (float*)(ws + 9437184);                 // 67,108,864
    double* fgbuf             = (double*)(ws + 76546048);               //  2,359,296
    unsigned long long* keys  = (unsigned long long*)(ws + 78905344);   //  2,359,296
    unsigned long long* kth   = (unsigned long long*)(ws + 81264640);   //        64 (pad 512)
    unsigned int* cnt         = (unsigned int*)(ws + 81265152);         //        32 (pad 512)
    unsigned long long* cbuf  = (unsigned long long*)(ws + 81265664);   //    524,288
    float* bsort              = (float*)(ws + 81789952);                //    768,000
    unsigned char* vflag      = (unsigned char*)(ws + 82557952);        //     48,128
    unsigned long long* masks = (unsigned long long*)(ws + 82606080);   // 36,096,000 -> ~118.7MB

    hipMemsetAsync(cnt, 0, 8 * 4, stream);

    dim3 gw(72, 16);
    k_wreord<<<gw, 256, 0, stream>>>(w1, wr);
    dim3 g3(16, 16, 8);
    k_conv3<<<g3, 256, 0, stream>>>(x, wr, b1, mid);
    dim3 g1(64, 8);
    k_conv1<<<g1, 256, 0, stream>>>(mid, wlc, blc, wsc, bsc, out, fgbuf);
    k_keys<<<1152, 256, 0, stream>>>(out, fgbuf, keys);
    k_select<<<8, 1024, 0, stream>>>(keys, kth);
    k_compact<<<1152, 256, 0, stream>>>(keys, kth, cbuf, cnt);
    k_sort<<<8, 1024, 0, stream>>>(cbuf, out, bsort, vflag);
    dim3 gm(24, 8);
    k_mask<<<gm, 256, 0, stream>>>(bsort, masks);
    k_scan<<<8, 128, 0, stream>>>(masks, vflag, bsort, out);
    k_anchor<<<144, 256, 0, stream>>>(out);
}

// Round 5
// 4225.944 us; speedup vs baseline: 1.2790x; 1.1458x over previous
//
#include <hip/hip_runtime.h>
#include <cstdint>
#include <cstddef>

#define CIN 512
#define NA 36864           // 4096 positions * 9 anchors
#define NPRE 6000
#define NPOST 300
#define CBUF_CAP 8192
#define NWORD 94           // ceil(6000/64)
#define NEGV -1000000000.0f

// d_out float offsets (return-order concat)
#define O_LOCS   0
#define O_SCORES 1179648   // 8*36864*4
#define O_ROIS   1769472   // + 8*36864*2
#define O_RIDX   1779072   // + 8*300*4
#define O_ANCH   1781472   // + 8*300

// ---------- exact-rounding helpers (ordering-critical code only) --------------------
__device__ __forceinline__ float fmulr(float a, float b) { return __fmul_rn(a, b); }
__device__ __forceinline__ float faddr(float a, float b) { return __fadd_rn(a, b); }
__device__ __forceinline__ float fsubr(float a, float b) { return __fsub_rn(a, b); }

__device__ __forceinline__ void anchor_for(int a, int pos, float* anc) {
    const double rat[3] = {0.5, 1.0, 2.0};
    const double scl[3] = {8.0, 16.0, 32.0};
    int ri = a / 3, si = a - ri * 3;
    double h = 16.0 * scl[si] * sqrt(rat[ri]);
    double w = 16.0 * scl[si] * sqrt(1.0 / rat[ri]);
    float a0 = (float)(8.0 - h * 0.5);
    float a1 = (float)(8.0 - w * 0.5);
    float a2 = (float)(8.0 + h * 0.5);
    float a3 = (float)(8.0 + w * 0.5);
    int y = pos >> 6, x = pos & 63;
    float sy = (float)(y * 16), sx = (float)(x * 16);
    anc[0] = faddr(a0, sy); anc[1] = faddr(a1, sx);
    anc[2] = faddr(a2, sy); anc[3] = faddr(a3, sx);
}

__device__ __forceinline__ bool decode_box(float4 L, const float* anc, float* box) {
    float ah  = fsubr(anc[2], anc[0]);
    float aw  = fsubr(anc[3], anc[1]);
    float acy = faddr(anc[0], fmulr(0.5f, ah));
    float acx = faddr(anc[1], fmulr(0.5f, aw));
    float cy  = faddr(fmulr(L.x, ah), acy);
    float cx  = faddr(fmulr(L.y, aw), acx);
    float h   = fmulr(ah, expf(L.z));
    float w   = fmulr(aw, expf(L.w));
    float y1 = fminf(fmaxf(fsubr(cy, fmulr(0.5f, h)), 0.0f), 1024.0f);
    float x1 = fminf(fmaxf(fsubr(cx, fmulr(0.5f, w)), 0.0f), 1024.0f);
    float y2 = fminf(fmaxf(faddr(cy, fmulr(0.5f, h)), 0.0f), 1024.0f);
    float x2 = fminf(fmaxf(faddr(cx, fmulr(0.5f, w)), 0.0f), 1024.0f);
    box[0] = y1; box[1] = x1; box[2] = y2; box[3] = x2;
    float hs = fsubr(y2, y1), ws2 = fsubr(x2, x1);
    return (hs >= 16.0f) && (ws2 >= 16.0f);
}

// monotonic 64-bit map of a double (totally ordered, sign handled)
__device__ __forceinline__ unsigned long long mono64(double f) {
    unsigned long long u = (unsigned long long)__double_as_longlong(f);
    return (u & 0x8000000000000000ull) ? ~u : (u | 0x8000000000000000ull);
}

// ---------------- weight reorder: w1[oc][c][ky][kx] -> wr[(c*9+tap)*512+oc] ----------
// LDS-tiled transpose: coalesced reads AND writes.
__global__ __launch_bounds__(256) void k_wreord(const float* __restrict__ w1,
                                                float* __restrict__ wr) {
    __shared__ float tile[32][65];
    const int ct0 = blockIdx.x * 64;   // 72 tiles over 4608 (c*9+tap)
    const int oc0 = blockIdx.y * 32;   // 16 tiles over 512
    const int t = threadIdx.x;
    for (int i = t; i < 32 * 64; i += 256) {
        int r = i >> 6, c = i & 63;
        tile[r][c] = w1[(size_t)(oc0 + r) * 4608 + ct0 + c];
    }
    __syncthreads();
    for (int i = t; i < 32 * 64; i += 256) {
        int cl = i >> 5, ol = i & 31;
        wr[(size_t)(ct0 + cl) * 512 + oc0 + ol] = tile[ol][cl];
    }
}

// ---------------- 3x3 conv 512->512 + bias + relu, pure fp32 -------------------------
// block: 64 oc x 4 rows x 64 cols, 256 threads; per-thread 8 oc x 8 cols.
// Two-level fp32 accumulation: sub[8][8] per 8-channel iter (72 taps), merged into
// acc[8][8]. mid error sigma ~6e-8 (same class as the twice-passing f64-merge version;
// fg ordering margin ~50x). No f64 -> no AGPR round-trips.
__global__ __launch_bounds__(256) void k_conv3(const float* __restrict__ x,
                                               const float* __restrict__ wr,
                                               const float* __restrict__ b1,
                                               float* __restrict__ mid) {
    __shared__ float in_s[8 * 6 * 68];   // [cc][rr(6)][xi(68)]  13056 floats
    __shared__ float w_s[8 * 9 * 64];    // [cc][tap][oc64]       4608 floats
    const int yb  = blockIdx.x;          // 16
    const int ocb = blockIdx.y;          // 8
    const int n   = blockIdx.z;          // 8
    const int t   = threadIdx.x;
    const int y0  = yb * 4;
    const int tocg = t >> 5;             // 0..7 -> oc group of 8
    const int tx   = t & 31;
    const int r    = tx >> 3;            // 0..3 row
    const int xo   = (tx & 7) << 3;      // 0..56 col octet

    float acc[8][8];
#pragma unroll
    for (int i = 0; i < 8; i++)
#pragma unroll
        for (int j = 0; j < 8; j++) acc[i][j] = 0.f;

    for (int ch = 0; ch < 64; ++ch) {
        const int c0 = ch * 8;
        for (int idx = t; idx < 4608; idx += 256) {
            int cc = idx / 576, rem = idx - cc * 576;
            int tap = rem >> 6, o = rem & 63;
            w_s[idx] = wr[((c0 + cc) * 9 + tap) * 512 + (ocb << 6) + o];
        }
        for (int idx = t; idx < 3264; idx += 256) {
            int cc = idx / 408, rem = idx - cc * 408;
            int rr = rem / 68, xi = rem - rr * 68;
            int gy = y0 - 1 + rr, gx = xi - 1;
            float v = 0.f;
            if (gy >= 0 && gy < 64 && xi >= 1 && xi <= 64)
                v = x[((n * CIN + c0 + cc) * 64 + gy) * 64 + gx];
            in_s[idx] = v;
        }
        __syncthreads();
        float sub[8][8];
#pragma unroll
        for (int i = 0; i < 8; i++)
#pragma unroll
            for (int j = 0; j < 8; j++) sub[i][j] = 0.f;
#pragma unroll 1
        for (int cc = 0; cc < 8; ++cc) {
#pragma unroll
            for (int dy = 0; dy < 3; ++dy) {
                const float4* ip = (const float4*)&in_s[cc * 408 + (r + dy) * 68 + xo];
                float4 A = ip[0], B = ip[1], C4 = ip[2];
                float in12[12] = {A.x, A.y, A.z, A.w, B.x, B.y, B.z, B.w,
                                  C4.x, C4.y, C4.z, C4.w};
#pragma unroll
                for (int dx = 0; dx < 3; ++dx) {
                    const float4* wp =
                        (const float4*)&w_s[cc * 576 + (dy * 3 + dx) * 64 + tocg * 8];
                    float4 W0 = wp[0], W1 = wp[1];
                    float w8[8] = {W0.x, W0.y, W0.z, W0.w, W1.x, W1.y, W1.z, W1.w};
#pragma unroll
                    for (int i = 0; i < 8; i++)
#pragma unroll
                        for (int j = 0; j < 8; j++)
                            sub[i][j] += w8[i] * in12[j + dx];
                }
            }
        }
#pragma unroll
        for (int i = 0; i < 8; i++)
#pragma unroll
            for (int j = 0; j < 8; j++) acc[i][j] += sub[i][j];
        __syncthreads();
    }
    const int ocbase = (ocb << 6) + tocg * 8;
#pragma unroll
    for (int i = 0; i < 8; i++) {
        float bb = b1[ocbase + i];
#pragma unroll
        for (int j = 0; j < 8; j++) {
            float v = fmaxf(acc[i][j] + bb, 0.f);
            mid[((n * CIN + ocbase + i) * 64 + (y0 + r)) * 64 + xo + j] = v;
        }
    }
}

// ---------------- fused 1x1 convs (36 loc + 18 score), f64 accumulation --------------
// also computes the f64 softmax fg score per anchor into fgbuf (ordering-critical).
__global__ __launch_bounds__(256) void k_conv1(const float* __restrict__ mid,
                                               const float* __restrict__ wl,
                                               const float* __restrict__ bl,
                                               const float* __restrict__ wsc,
                                               const float* __restrict__ bs,
                                               float* __restrict__ out,
                                               double* __restrict__ fgbuf) {
    __shared__ float in_s[128 * 64];
    __shared__ float w_s[54 * 128];
    const int y = blockIdx.x;   // 64
    const int n = blockIdx.y;   // 8
    const int t = threadIdx.x;
    const int xx = t & 63, og = t >> 6;   // og uniform per wave
    double accd[14];
#pragma unroll
    for (int k = 0; k < 14; k++) accd[k] = 0.0;

    for (int c0 = 0; c0 < 512; c0 += 128) {
        for (int idx = t; idx < 128 * 64; idx += 256) {
            int cc = idx >> 6, x2 = idx & 63;
            in_s[idx] = mid[((n * CIN + c0 + cc) * 64 + y) * 64 + x2];
        }
        for (int idx = t; idx < 54 * 128; idx += 256) {
            int oc = idx >> 7, cc = idx & 127;
            w_s[idx] = (oc < 36) ? wl[oc * 512 + c0 + cc] : wsc[(oc - 36) * 512 + c0 + cc];
        }
        __syncthreads();
#pragma unroll 1
        for (int cc = 0; cc < 128; ++cc) {
            double iv = (double)in_s[cc * 64 + xx];
#pragma unroll
            for (int k = 0; k < 14; k++) {
                int oc = og * 14 + k;
                if (oc < 54) accd[k] += (double)w_s[oc * 128 + cc] * iv;
            }
        }
        __syncthreads();
    }
    const int pos = y * 64 + xx;
    double sv[14];
#pragma unroll
    for (int k = 0; k < 14; k++) {
        int oc = og * 14 + k;
        if (oc >= 54) break;
        if (oc < 36) {
            double v = accd[k] + (double)bl[oc];
            int a = oc >> 2, cd = oc & 3;
            out[O_LOCS + ((size_t)(n * NA + pos * 9 + a)) * 4 + cd] = (float)v;
        } else {
            sv[k] = accd[k] + (double)bs[oc - 36];
            int c2 = oc - 36, a = c2 >> 1, cls = c2 & 1;
            out[O_SCORES + ((size_t)(n * NA + pos * 9 + a)) * 2 + cls] = (float)sv[k];
        }
    }
#pragma unroll
    for (int k = 0; k < 13; k++) {
        int oc = og * 14 + k;
        if (oc >= 36 && oc < 54 && ((oc - 36) & 1) == 0) {
            double s0 = sv[k], s1 = sv[k + 1];
            double m = fmax(s0, s1);
            double e0 = exp(s0 - m), e1 = exp(s1 - m);
            double fg = e1 / (e0 + e1);
            int a = (oc - 36) >> 1;
            fgbuf[(size_t)n * NA + pos * 9 + a] = fg;
        }
    }
}

// ---------------- keys: mono64(f64 fg) with low 16 bits = inverted index -------------
__global__ __launch_bounds__(256) void k_keys(const float* __restrict__ out,
                                              const double* __restrict__ fgbuf,
                                              unsigned long long* __restrict__ keys) {
    const int n = blockIdx.x / 144;
    const int i = (blockIdx.x % 144) * 256 + threadIdx.x;
    int pos = i / 9, a = i - pos * 9;
    float anc[4]; anchor_for(a, pos, anc);
    float4 L = *(const float4*)&out[O_LOCS + (size_t)(n * NA + i) * 4];
    float box[4];
    bool ok = decode_box(L, anc, box);
    double f = ok ? fgbuf[(size_t)n * NA + i] : (double)NEGV;
    unsigned long long m = mono64(f);
    keys[(size_t)n * NA + i] =
        (m & 0xFFFFFFFFFFFF0000ull) | (unsigned long long)(0xFFFFu - (unsigned)i);
}

// ---------------- exact 64-bit radix select: kth[n] = 6000th largest key -------------
// 5 levels: 13+13+13+13+12 bits. Keys unique -> count(key >= kth) == 6000 exactly.
__global__ __launch_bounds__(1024) void k_select(const unsigned long long* __restrict__ keys,
                                                 unsigned long long* __restrict__ kth) {
    __shared__ unsigned int hist[8192];
    __shared__ unsigned int gs[256];
    __shared__ unsigned long long s_pref;
    __shared__ int s_plen, s_rem;
    const int n = blockIdx.x, t = threadIdx.x;
    if (t == 0) { s_pref = 0ull; s_plen = 0; s_rem = NPRE; }
    __syncthreads();
    const int shifts[5] = {51, 38, 25, 12, 0};
    const int widths[5] = {13, 13, 13, 13, 12};
    for (int lev = 0; lev < 5; ++lev) {
        const int nb = 1 << widths[lev];
        for (int b = t; b < nb; b += 1024) hist[b] = 0;
        __syncthreads();
        const unsigned long long pref = s_pref;
        const int plen = s_plen;
        for (int i = t; i < NA; i += 1024) {
            unsigned long long key = keys[(size_t)n * NA + i];
            if (plen == 0 || (key >> (64 - plen)) == pref) {
                unsigned int bin = (unsigned int)((key >> shifts[lev]) & (unsigned)(nb - 1));
                atomicAdd(&hist[bin], 1u);
            }
        }
        __syncthreads();
        const int gsz = nb >> 8;   // bins per thread-group
        if (t < 256) {
            unsigned int s = 0;
            for (int m = 0; m < gsz; m++) s += hist[t * gsz + m];
            gs[t] = s;
        }
        __syncthreads();
        if (t == 0) {
            const unsigned int rem = (unsigned int)s_rem;
            unsigned int acc = 0; int selbin = 0;
            for (int g = 255; g >= 0; --g) {
                if (acc + gs[g] >= rem) {
                    for (int b = g * gsz + gsz - 1; b >= g * gsz; --b) {
                        if (acc + hist[b] >= rem) { selbin = b; break; }
                        acc += hist[b];
                    }
                    break;
                }
                acc += gs[g];
            }
            s_rem = (int)(rem - acc);
            s_pref = (s_pref << widths[lev]) | (unsigned long long)(unsigned)selbin;
            s_plen += widths[lev];
        }
        __syncthreads();
    }
    if (t == 0) kth[n] = s_pref;
}

// ---------------- compact: exactly the 6000 keys >= kth ------------------------------
__global__ void k_compact(const unsigned long long* __restrict__ keys,
                          const unsigned long long* __restrict__ kth,
                          unsigned long long* __restrict__ cbuf,
                          unsigned int* __restrict__ cnt) {
    const int n = blockIdx.x / 144;
    const int i = (blockIdx.x % 144) * 256 + threadIdx.x;
    unsigned long long key = keys[(size_t)n * NA + i];
    if (key >= kth[n]) {
        unsigned int p = atomicAdd(&cnt[n], 1u);
        if (p < CBUF_CAP) cbuf[(size_t)n * CBUF_CAP + p] = key;
    }
}

// ---------------- per-image LDS bitonic sort (descending), emit top-6000 boxes -------
__global__ __launch_bounds__(1024) void k_sort(const unsigned long long* __restrict__ cbuf,
                                               const float* __restrict__ out,
                                               float* __restrict__ bsort,
                                               unsigned char* __restrict__ vflag) {
    __shared__ unsigned long long arr[CBUF_CAP];
    const int n = blockIdx.x, t = threadIdx.x;
    for (int idx = t; idx < CBUF_CAP; idx += 1024)
        arr[idx] = (idx < NPRE) ? cbuf[(size_t)n * CBUF_CAP + idx] : 0ull;
    __syncthreads();
    for (int k = 2; k <= CBUF_CAP; k <<= 1)
        for (int j = k >> 1; j > 0; j >>= 1) {
            for (int i = t; i < CBUF_CAP; i += 1024) {
                int ixj = i ^ j;
                if (ixj > i) {
                    unsigned long long a = arr[i], b = arr[ixj];
                    bool up = (i & k) == 0;
                    if (up ? (a < b) : (a > b)) { arr[i] = b; arr[ixj] = a; }
                }
            }
            __syncthreads();
        }
    for (int r = t; r < NPRE; r += 1024) {
        unsigned long long key = arr[r];
        unsigned int i = 0xFFFFu - (unsigned int)(key & 0xFFFFull);
        int pos = i / 9, a = i - pos * 9;
        float anc[4]; anchor_for(a, pos, anc);
        float4 L = *(const float4*)&out[O_LOCS + (size_t)(n * NA + i) * 4];
        float box[4];
        bool ok = decode_box(L, anc, box);
        ((float4*)bsort)[(size_t)n * NPRE + r] = make_float4(box[0], box[1], box[2], box[3]);
        vflag[(size_t)n * NPRE + r] = ok ? 1 : 0;
    }
}

// ---------------- suppression bitmask matrix (bits j>i with IoU>0.7) -----------------
__global__ __launch_bounds__(256) void k_mask(const float* __restrict__ bsort,
                                              unsigned long long* __restrict__ masks) {
    __shared__ float4 bx[1024];
    const int n = blockIdx.y;
    const int i = blockIdx.x * 256 + threadIdx.x;
    const bool have = i < NPRE;
    float4 bi = make_float4(0, 0, 0, 0); float areai = 0.f;
    if (have) {
        bi = ((const float4*)bsort)[(size_t)n * NPRE + i];
        areai = fmulr(fsubr(bi.z, bi.x), fsubr(bi.w, bi.y));
    }
    for (int jc = 0; jc < 6; ++jc) {
        int jn = min(1024, NPRE - jc * 1024);
        __syncthreads();
        for (int jj = threadIdx.x; jj < jn; jj += 256)
            bx[jj] = ((const float4*)bsort)[(size_t)n * NPRE + jc * 1024 + jj];
        __syncthreads();
        for (int w = 0; w < 16; ++w) {
            int gw = jc * 16 + w;
            if (gw >= NWORD) break;
            unsigned long long m = 0ull;
            int jbase = jc * 1024 + w * 64;
            if (have && jbase + 63 > i) {
#pragma unroll 1
                for (int b = 0; b < 64; b++) {
                    int j = jbase + b;
                    if (j > i && j < NPRE) {
                        float4 bj = bx[w * 64 + b];
                        float ih = fmaxf(fsubr(fminf(bi.z, bj.z), fmaxf(bi.x, bj.x)), 0.f);
                        float iw = fmaxf(fsubr(fminf(bi.w, bj.w), fmaxf(bi.y, bj.y)), 0.f);
                        float inter = fmulr(ih, iw);
                        float areaj = fmulr(fsubr(bj.z, bj.x), fsubr(bj.w, bj.y));
                        float den = faddr(fsubr(faddr(areai, areaj), inter), 1e-9f);
                        float iou = __fdiv_rn(inter, den);
                        if (iou > 0.7f) m |= (1ull << b);
                    }
                }
            }
            if (have) masks[((size_t)n * NPRE + i) * NWORD + gw] = m;
        }
    }
}

// ---------------- serial greedy scan with early exit at 300 kept ---------------------
__global__ __launch_bounds__(128) void k_scan(const unsigned long long* __restrict__ masks,
                                              const unsigned char* __restrict__ vflag,
                                              const float* __restrict__ bsort,
                                              float* __restrict__ out) {
    __shared__ unsigned long long sup[NWORD];
    __shared__ unsigned long long valw[NWORD];
    __shared__ int kept;
    const int n = blockIdx.x, t = threadIdx.x;
    if (t == 0) kept = 0;
    if (t < NWORD) {
        sup[t] = 0ull;
        unsigned long long v = 0ull;
        for (int b = 0; b < 64; b++) {
            int r = t * 64 + b;
            if (r < NPRE && vflag[(size_t)n * NPRE + r]) v |= (1ull << b);
        }
        valw[t] = v;
    }
    __syncthreads();
    for (int i = 0; i < NPRE; ++i) {
        bool keep = ((valw[i >> 6] >> (i & 63)) & 1ull) && !((sup[i >> 6] >> (i & 63)) & 1ull);
        if (keep) {
            if (t < NWORD) sup[t] |= masks[((size_t)n * NPRE + i) * NWORD + t];
            if (t == 0) {
                int r = kept;
                if (r < NPOST) {
                    float4 b4 = ((const float4*)bsort)[(size_t)n * NPRE + i];
                    out[O_ROIS + (size_t)(n * NPOST + r) * 4 + 0] = b4.x;
                    out[O_ROIS + (size_t)(n * NPOST + r) * 4 + 1] = b4.y;
                    out[O_ROIS + (size_t)(n * NPOST + r) * 4 + 2] = b4.z;
                    out[O_ROIS + (size_t)(n * NPOST + r) * 4 + 3] = b4.w;
                    out[O_RIDX + n * NPOST + r] = (float)n;
                }
                kept = r + 1;
            }
            __syncthreads();
            if (kept >= NPOST) break;
        }
    }
    __syncthreads();
    for (int r = kept + t; r < NPOST; r += 128) {
        out[O_ROIS + (size_t)(n * NPOST + r) * 4 + 0] = 0.f;
        out[O_ROIS + (size_t)(n * NPOST + r) * 4 + 1] = 0.f;
        out[O_ROIS + (size_t)(n * NPOST + r) * 4 + 2] = 0.f;
        out[O_ROIS + (size_t)(n * NPOST + r) * 4 + 3] = 0.f;
        out[O_RIDX + n * NPOST + r] = -1.0f;
    }
}

// ---------------- anchors output ------------------------------------------------------
__global__ void k_anchor(float* __restrict__ out) {
    int i = blockIdx.x * 256 + threadIdx.x;
    if (i >= NA) return;
    int pos = i / 9, a = i - pos * 9;
    float anc[4]; anchor_for(a, pos, anc);
    out[O_ANCH + (size_t)i * 4 + 0] = anc[0];
    out[O_ANCH + (size_t)i * 4 + 1] = anc[1];
    out[O_ANCH + (size_t)i * 4 + 2] = anc[2];
    out[O_ANCH + (size_t)i * 4 + 3] = anc[3];
}

extern "C" void kernel_launch(void* const* d_in, const int* in_sizes, int n_in,
                              void* d_out, int out_size, void* d_ws, size_t ws_size,
                              hipStream_t stream) {
    const float* x   = (const float*)d_in[0];
    const float* w1  = (const float*)d_in[1];
    const float* b1  = (const float*)d_in[2];
    const float* wsc = (const float*)d_in[3];
    const float* bsc = (const float*)d_in[4];
    const float* wlc = (const float*)d_in[5];
    const float* blc = (const float*)d_in[6];
    float* out = (float*)d_out;
    char* ws = (char*)d_ws;

    float* wr                 = (float*)(ws + 0);                       //  9,437,184
    float* mid                = (float*)(ws + 9437184);                 // 67,108,864
    double* fgbuf             = (double*)(ws + 76546048);               //  2,359,296
    unsigned long long* keys  = (unsigned long long*)(ws + 78905344);   //  2,359,296
    unsigned long long* kth   = (unsigned long long*)(ws + 81264640);   //        64 (pad 512)
    unsigned int* cnt         = (unsigned int*)(ws + 81265152);         //        32 (pad 512)
    unsigned long long* cbuf  = (unsigned long long*)(ws + 81265664);   //    524,288
    float* bsort              = (float*)(ws + 81789952);                //    768,000
    unsigned char* vflag      = (unsigned char*)(ws + 82557952);        //     48,128
    unsigned long long* masks = (unsigned long long*)(ws + 82606080);   // 36,096,000 -> ~118.7MB

    hipMemsetAsync(cnt, 0, 8 * 4, stream);

    dim3 gw(72, 16);
    k_wreord<<<gw, 256, 0, stream>>>(w1, wr);
    dim3 g3(16, 8, 8);
    k_conv3<<<g3, 256, 0, stream>>>(x, wr, b1, mid);
    dim3 g1(64, 8);
    k_conv1<<<g1, 256, 0, stream>>>(mid, wlc, blc, wsc, bsc, out, fgbuf);
    k_keys<<<1152, 256, 0, stream>>>(out, fgbuf, keys);
    k_select<<<8, 1024, 0, stream>>>(keys, kth);
    k_compact<<<1152, 256, 0, stream>>>(keys, kth, cbuf, cnt);
    k_sort<<<8, 1024, 0, stream>>>(cbuf, out, bsort, vflag);
    dim3 gm(24, 8);
    k_mask<<<gm, 256, 0, stream>>>(bsort, masks);
    k_scan<<<8, 128, 0, stream>>>(masks, vflag, bsort, out);
    k_anchor<<<144, 256, 0, stream>>>(out);
}

// Round 6
// 3602.832 us; speedup vs baseline: 1.5002x; 1.1730x over previous
//
#include <hip/hip_runtime.h>
#include <cstdint>
#include <cstddef>

#define CIN 512
#define NA 36864           // 4096 positions * 9 anchors
#define NPRE 6000
#define NPOST 300
#define CBUF_CAP 8192
#define NWORD 94           // ceil(6000/64)
#define NEGV -1000000000.0f

// d_out float offsets (return-order concat)
#define O_LOCS   0
#define O_SCORES 1179648   // 8*36864*4
#define O_ROIS   1769472   // + 8*36864*2
#define O_RIDX   1779072   // + 8*300*4
#define O_ANCH   1781472   // + 8*300

// ---------- exact-rounding helpers (ordering-critical code only) --------------------
__device__ __forceinline__ float fmulr(float a, float b) { return __fmul_rn(a, b); }
__device__ __forceinline__ float faddr(float a, float b) { return __fadd_rn(a, b); }
__device__ __forceinline__ float fsubr(float a, float b) { return __fsub_rn(a, b); }

__device__ __forceinline__ void anchor_for(int a, int pos, float* anc) {
    const double rat[3] = {0.5, 1.0, 2.0};
    const double scl[3] = {8.0, 16.0, 32.0};
    int ri = a / 3, si = a - ri * 3;
    double h = 16.0 * scl[si] * sqrt(rat[ri]);
    double w = 16.0 * scl[si] * sqrt(1.0 / rat[ri]);
    float a0 = (float)(8.0 - h * 0.5);
    float a1 = (float)(8.0 - w * 0.5);
    float a2 = (float)(8.0 + h * 0.5);
    float a3 = (float)(8.0 + w * 0.5);
    int y = pos >> 6, x = pos & 63;
    float sy = (float)(y * 16), sx = (float)(x * 16);
    anc[0] = faddr(a0, sy); anc[1] = faddr(a1, sx);
    anc[2] = faddr(a2, sy); anc[3] = faddr(a3, sx);
}

__device__ __forceinline__ bool decode_box(float4 L, const float* anc, float* box) {
    float ah  = fsubr(anc[2], anc[0]);
    float aw  = fsubr(anc[3], anc[1]);
    float acy = faddr(anc[0], fmulr(0.5f, ah));
    float acx = faddr(anc[1], fmulr(0.5f, aw));
    float cy  = faddr(fmulr(L.x, ah), acy);
    float cx  = faddr(fmulr(L.y, aw), acx);
    float h   = fmulr(ah, expf(L.z));
    float w   = fmulr(aw, expf(L.w));
    float y1 = fminf(fmaxf(fsubr(cy, fmulr(0.5f, h)), 0.0f), 1024.0f);
    float x1 = fminf(fmaxf(fsubr(cx, fmulr(0.5f, w)), 0.0f), 1024.0f);
    float y2 = fminf(fmaxf(faddr(cy, fmulr(0.5f, h)), 0.0f), 1024.0f);
    float x2 = fminf(fmaxf(faddr(cx, fmulr(0.5f, w)), 0.0f), 1024.0f);
    box[0] = y1; box[1] = x1; box[2] = y2; box[3] = x2;
    float hs = fsubr(y2, y1), ws2 = fsubr(x2, x1);
    return (hs >= 16.0f) && (ws2 >= 16.0f);
}

// monotonic 64-bit map of a double (totally ordered, sign handled)
__device__ __forceinline__ unsigned long long mono64(double f) {
    unsigned long long u = (unsigned long long)__double_as_longlong(f);
    return (u & 0x8000000000000000ull) ? ~u : (u | 0x8000000000000000ull);
}

// ---------------- weight reorder: w1[oc][c][ky][kx] -> wr2[ocb][ct(c*9+tap)][o32] ----
// LDS-tiled transpose: coalesced reads AND writes. Layout matches conv3 LDS exactly,
// so conv3's weight staging is a pure linear copy (zero address math).
__global__ __launch_bounds__(256) void k_wreord(const float* __restrict__ w1,
                                                float* __restrict__ wr2) {
    __shared__ float tile[32][73];
    const int ct0 = blockIdx.x * 72;   // 64 chunks over 4608 (c*9+tap)
    const int ocb = blockIdx.y;        // 16
    const int t = threadIdx.x;
    for (int i = t; i < 32 * 72; i += 256) {
        int orow = i / 72, ct = i - orow * 72;
        tile[orow][ct] = w1[(size_t)(ocb * 32 + orow) * 4608 + ct0 + ct];
    }
    __syncthreads();
    for (int i = t; i < 72 * 32; i += 256) {
        int ct = i >> 5, o = i & 31;
        wr2[((size_t)ocb * 4608 + ct0 + ct) * 32 + o] = tile[o][ct];
    }
}

// ---------------- 3x3 conv 512->512 + bias + relu, pure fp32 -------------------------
// block: 32 oc x 4 rows x 64 cols, 256 threads; per-thread 4 oc x 8 cols.
// Two-level fp32 accumulation, summation tree IDENTICAL to round-5 (8ch x 9tap fp32
// sub-chunk, cc-major/dy/dx order, merged into fp32 acc) -> bit-identical mid.
// acc+sub = 64 regs; launch_bounds(256,4) keeps everything in <=128 VGPR ->
// 4 waves/SIMD so inter-block overlap hides the staging barrier drain.
__global__ __launch_bounds__(256, 4) void k_conv3(const float* __restrict__ x,
                                                  const float* __restrict__ wr2,
                                                  const float* __restrict__ b1,
                                                  float* __restrict__ mid) {
    __shared__ float in_s[8 * 6 * 68];   // [cc][rr(6)][xi(68)]  3264 floats
    __shared__ float w_s[8 * 9 * 32];    // [cc][tap][o32]       2304 floats
    const int yb  = blockIdx.x;          // 16
    const int ocb = blockIdx.y;          // 16
    const int n   = blockIdx.z;          // 8
    const int t   = threadIdx.x;
    const int y0  = yb * 4;
    const int tocg = t >> 5;             // 0..7 -> oc group of 4
    const int tx   = t & 31;
    const int r    = tx >> 3;            // 0..3 row
    const int xo   = (tx & 7) << 3;      // 0..56 col octet

    float acc[4][8];
#pragma unroll
    for (int i = 0; i < 4; i++)
#pragma unroll
        for (int j = 0; j < 8; j++) acc[i][j] = 0.f;

    const size_t wblk = (size_t)ocb * 4608 * 32;
    for (int ch = 0; ch < 64; ++ch) {
        const int c0 = ch * 8;
        // weights: pure linear copy, 9 floats/thread
        const size_t wbase = wblk + (size_t)c0 * 9 * 32;
#pragma unroll
        for (int k = 0; k < 9; ++k)
            w_s[t + k * 256] = wr2[wbase + t + k * 256];
        // input tile with halo
        for (int idx = t; idx < 3264; idx += 256) {
            int cc = idx / 408, rem = idx - cc * 408;
            int rr = rem / 68, xi = rem - rr * 68;
            int gy = y0 - 1 + rr, gx = xi - 1;
            float v = 0.f;
            if (gy >= 0 && gy < 64 && xi >= 1 && xi <= 64)
                v = x[((n * CIN + c0 + cc) * 64 + gy) * 64 + gx];
            in_s[idx] = v;
        }
        __syncthreads();
        float sub[4][8];
#pragma unroll
        for (int i = 0; i < 4; i++)
#pragma unroll
            for (int j = 0; j < 8; j++) sub[i][j] = 0.f;
#pragma unroll 1
        for (int cc = 0; cc < 8; ++cc) {
#pragma unroll
            for (int dy = 0; dy < 3; ++dy) {
                const float4* ip = (const float4*)&in_s[cc * 408 + (r + dy) * 68 + xo];
                float4 A = ip[0], B = ip[1], C4 = ip[2];
                float in12[12] = {A.x, A.y, A.z, A.w, B.x, B.y, B.z, B.w,
                                  C4.x, C4.y, C4.z, C4.w};
#pragma unroll
                for (int dx = 0; dx < 3; ++dx) {
                    const float4* wp =
                        (const float4*)&w_s[cc * 288 + (dy * 3 + dx) * 32 + tocg * 4];
                    float4 W0 = wp[0];
                    float w4[4] = {W0.x, W0.y, W0.z, W0.w};
#pragma unroll
                    for (int i = 0; i < 4; i++)
#pragma unroll
                        for (int j = 0; j < 8; j++)
                            sub[i][j] += w4[i] * in12[j + dx];
                }
            }
        }
#pragma unroll
        for (int i = 0; i < 4; i++)
#pragma unroll
            for (int j = 0; j < 8; j++) acc[i][j] += sub[i][j];
        __syncthreads();
    }
    const int ocbase = ocb * 32 + tocg * 4;
#pragma unroll
    for (int i = 0; i < 4; i++) {
        float bb = b1[ocbase + i];
#pragma unroll
        for (int j = 0; j < 8; j++) {
            float v = fmaxf(acc[i][j] + bb, 0.f);
            mid[((n * CIN + ocbase + i) * 64 + (y0 + r)) * 64 + xo + j] = v;
        }
    }
}

// ---------------- fused 1x1 convs (36 loc + 18 score), f64 accumulation --------------
// also computes the f64 softmax fg score per anchor into fgbuf (ordering-critical).
__global__ __launch_bounds__(256) void k_conv1(const float* __restrict__ mid,
                                               const float* __restrict__ wl,
                                               const float* __restrict__ bl,
                                               const float* __restrict__ wsc,
                                               const float* __restrict__ bs,
                                               float* __restrict__ out,
                                               double* __restrict__ fgbuf) {
    __shared__ float in_s[128 * 64];
    __shared__ float w_s[54 * 128];
    const int y = blockIdx.x;   // 64
    const int n = blockIdx.y;   // 8
    const int t = threadIdx.x;
    const int xx = t & 63, og = t >> 6;   // og uniform per wave
    double accd[14];
#pragma unroll
    for (int k = 0; k < 14; k++) accd[k] = 0.0;

    for (int c0 = 0; c0 < 512; c0 += 128) {
        for (int idx = t; idx < 128 * 64; idx += 256) {
            int cc = idx >> 6, x2 = idx & 63;
            in_s[idx] = mid[((n * CIN + c0 + cc) * 64 + y) * 64 + x2];
        }
        for (int idx = t; idx < 54 * 128; idx += 256) {
            int oc = idx >> 7, cc = idx & 127;
            w_s[idx] = (oc < 36) ? wl[oc * 512 + c0 + cc] : wsc[(oc - 36) * 512 + c0 + cc];
        }
        __syncthreads();
#pragma unroll 1
        for (int cc = 0; cc < 128; ++cc) {
            double iv = (double)in_s[cc * 64 + xx];
#pragma unroll
            for (int k = 0; k < 14; k++) {
                int oc = og * 14 + k;
                if (oc < 54) accd[k] += (double)w_s[oc * 128 + cc] * iv;
            }
        }
        __syncthreads();
    }
    const int pos = y * 64 + xx;
    double sv[14];
#pragma unroll
    for (int k = 0; k < 14; k++) {
        int oc = og * 14 + k;
        if (oc >= 54) break;
        if (oc < 36) {
            double v = accd[k] + (double)bl[oc];
            int a = oc >> 2, cd = oc & 3;
            out[O_LOCS + ((size_t)(n * NA + pos * 9 + a)) * 4 + cd] = (float)v;
        } else {
            sv[k] = accd[k] + (double)bs[oc - 36];
            int c2 = oc - 36, a = c2 >> 1, cls = c2 & 1;
            out[O_SCORES + ((size_t)(n * NA + pos * 9 + a)) * 2 + cls] = (float)sv[k];
        }
    }
#pragma unroll
    for (int k = 0; k < 13; k++) {
        int oc = og * 14 + k;
        if (oc >= 36 && oc < 54 && ((oc - 36) & 1) == 0) {
            double s0 = sv[k], s1 = sv[k + 1];
            double m = fmax(s0, s1);
            double e0 = exp(s0 - m), e1 = exp(s1 - m);
            double fg = e1 / (e0 + e1);
            int a = (oc - 36) >> 1;
            fgbuf[(size_t)n * NA + pos * 9 + a] = fg;
        }
    }
}

// ---------------- keys: mono64(f64 fg) with low 16 bits = inverted index -------------
__global__ __launch_bounds__(256) void k_keys(const float* __restrict__ out,
                                              const double* __restrict__ fgbuf,
                                              unsigned long long* __restrict__ keys) {
    const int n = blockIdx.x / 144;
    const int i = (blockIdx.x % 144) * 256 + threadIdx.x;
    int pos = i / 9, a = i - pos * 9;
    float anc[4]; anchor_for(a, pos, anc);
    float4 L = *(const float4*)&out[O_LOCS + (size_t)(n * NA + i) * 4];
    float box[4];
    bool ok = decode_box(L, anc, box);
    double f = ok ? fgbuf[(size_t)n * NA + i] : (double)NEGV;
    unsigned long long m = mono64(f);
    keys[(size_t)n * NA + i] =
        (m & 0xFFFFFFFFFFFF0000ull) | (unsigned long long)(0xFFFFu - (unsigned)i);
}

// ---------------- exact 64-bit radix select: kth[n] = 6000th largest key -------------
// 5 levels: 13+13+13+13+12 bits. Keys unique -> count(key >= kth) == 6000 exactly.
__global__ __launch_bounds__(1024) void k_select(const unsigned long long* __restrict__ keys,
                                                 unsigned long long* __restrict__ kth) {
    __shared__ unsigned int hist[8192];
    __shared__ unsigned int gs[256];
    __shared__ unsigned long long s_pref;
    __shared__ int s_plen, s_rem;
    const int n = blockIdx.x, t = threadIdx.x;
    if (t == 0) { s_pref = 0ull; s_plen = 0; s_rem = NPRE; }
    __syncthreads();
    const int shifts[5] = {51, 38, 25, 12, 0};
    const int widths[5] = {13, 13, 13, 13, 12};
    for (int lev = 0; lev < 5; ++lev) {
        const int nb = 1 << widths[lev];
        for (int b = t; b < nb; b += 1024) hist[b] = 0;
        __syncthreads();
        const unsigned long long pref = s_pref;
        const int plen = s_plen;
        for (int i = t; i < NA; i += 1024) {
            unsigned long long key = keys[(size_t)n * NA + i];
            if (plen == 0 || (key >> (64 - plen)) == pref) {
                unsigned int bin = (unsigned int)((key >> shifts[lev]) & (unsigned)(nb - 1));
                atomicAdd(&hist[bin], 1u);
            }
        }
        __syncthreads();
        const int gsz = nb >> 8;   // bins per thread-group
        if (t < 256) {
            unsigned int s = 0;
            for (int m = 0; m < gsz; m++) s += hist[t * gsz + m];
            gs[t] = s;
        }
        __syncthreads();
        if (t == 0) {
            const unsigned int rem = (unsigned int)s_rem;
            unsigned int acc = 0; int selbin = 0;
            for (int g = 255; g >= 0; --g) {
                if (acc + gs[g] >= rem) {
                    for (int b = g * gsz + gsz - 1; b >= g * gsz; --b) {
                        if (acc + hist[b] >= rem) { selbin = b; break; }
                        acc += hist[b];
                    }
                    break;
                }
                acc += gs[g];
            }
            s_rem = (int)(rem - acc);
            s_pref = (s_pref << widths[lev]) | (unsigned long long)(unsigned)selbin;
            s_plen += widths[lev];
        }
        __syncthreads();
    }
    if (t == 0) kth[n] = s_pref;
}

// ---------------- compact: exactly the 6000 keys >= kth ------------------------------
__global__ void k_compact(const unsigned long long* __restrict__ keys,
                          const unsigned long long* __restrict__ kth,
                          unsigned long long* __restrict__ cbuf,
                          unsigned int* __restrict__ cnt) {
    const int n = blockIdx.x / 144;
    const int i = (blockIdx.x % 144) * 256 + threadIdx.x;
    unsigned long long key = keys[(size_t)n * NA + i];
    if (key >= kth[n]) {
        unsigned int p = atomicAdd(&cnt[n], 1u);
        if (p < CBUF_CAP) cbuf[(size_t)n * CBUF_CAP + p] = key;
    }
}

// ---------------- per-image LDS bitonic sort (descending), emit top-6000 boxes -------
__global__ __launch_bounds__(1024) void k_sort(const unsigned long long* __restrict__ cbuf,
                                               const float* __restrict__ out,
                                               float* __restrict__ bsort,
                                               unsigned char* __restrict__ vflag) {
    __shared__ unsigned long long arr[CBUF_CAP];
    const int n = blockIdx.x, t = threadIdx.x;
    for (int idx = t; idx < CBUF_CAP; idx += 1024)
        arr[idx] = (idx < NPRE) ? cbuf[(size_t)n * CBUF_CAP + idx] : 0ull;
    __syncthreads();
    for (int k = 2; k <= CBUF_CAP; k <<= 1)
        for (int j = k >> 1; j > 0; j >>= 1) {
            for (int i = t; i < CBUF_CAP; i += 1024) {
                int ixj = i ^ j;
                if (ixj > i) {
                    unsigned long long a = arr[i], b = arr[ixj];
                    bool up = (i & k) == 0;
                    if (up ? (a < b) : (a > b)) { arr[i] = b; arr[ixj] = a; }
                }
            }
            __syncthreads();
        }
    for (int r = t; r < NPRE; r += 1024) {
        unsigned long long key = arr[r];
        unsigned int i = 0xFFFFu - (unsigned int)(key & 0xFFFFull);
        int pos = i / 9, a = i - pos * 9;
        float anc[4]; anchor_for(a, pos, anc);
        float4 L = *(const float4*)&out[O_LOCS + (size_t)(n * NA + i) * 4];
        float box[4];
        bool ok = decode_box(L, anc, box);
        ((float4*)bsort)[(size_t)n * NPRE + r] = make_float4(box[0], box[1], box[2], box[3]);
        vflag[(size_t)n * NPRE + r] = ok ? 1 : 0;
    }
}

// ---------------- suppression bitmask matrix (bits j>i with IoU>0.7) -----------------
// grid (24 i-chunks, 6 j-chunks, 8 n): 1152 blocks for latency hiding.
__global__ __launch_bounds__(256) void k_mask(const float* __restrict__ bsort,
                                              unsigned long long* __restrict__ masks) {
    __shared__ float4 bx[1024];
    const int n  = blockIdx.z;
    const int jc = blockIdx.y;
    const int i  = blockIdx.x * 256 + threadIdx.x;
    const bool have = i < NPRE;
    float4 bi = make_float4(0, 0, 0, 0); float areai = 0.f;
    if (have) {
        bi = ((const float4*)bsort)[(size_t)n * NPRE + i];
        areai = fmulr(fsubr(bi.z, bi.x), fsubr(bi.w, bi.y));
    }
    const int jn = min(1024, NPRE - jc * 1024);
    for (int jj = threadIdx.x; jj < jn; jj += 256)
        bx[jj] = ((const float4*)bsort)[(size_t)n * NPRE + jc * 1024 + jj];
    __syncthreads();
    for (int w = 0; w < 16; ++w) {
        int gw = jc * 16 + w;
        if (gw >= NWORD) break;
        unsigned long long m = 0ull;
        int jbase = jc * 1024 + w * 64;
        if (have && jbase + 63 > i) {
#pragma unroll 1
            for (int b = 0; b < 64; b++) {
                int j = jbase + b;
                if (j > i && j < NPRE) {
                    float4 bj = bx[w * 64 + b];
                    float ih = fmaxf(fsubr(fminf(bi.z, bj.z), fmaxf(bi.x, bj.x)), 0.f);
                    float iw = fmaxf(fsubr(fminf(bi.w, bj.w), fmaxf(bi.y, bj.y)), 0.f);
                    float inter = fmulr(ih, iw);
                    float areaj = fmulr(fsubr(bj.z, bj.x), fsubr(bj.w, bj.y));
                    float den = faddr(fsubr(faddr(areai, areaj), inter), 1e-9f);
                    float iou = __fdiv_rn(inter, den);
                    if (iou > 0.7f) m |= (1ull << b);
                }
            }
        }
        if (have) masks[((size_t)n * NPRE + i) * NWORD + gw] = m;
    }
}

// ---------------- serial greedy scan with early exit at 300 kept ---------------------
__global__ __launch_bounds__(128) void k_scan(const unsigned long long* __restrict__ masks,
                                              const unsigned char* __restrict__ vflag,
                                              const float* __restrict__ bsort,
                                              float* __restrict__ out) {
    __shared__ unsigned long long sup[NWORD];
    __shared__ unsigned long long valw[NWORD];
    __shared__ int kept;
    const int n = blockIdx.x, t = threadIdx.x;
    if (t == 0) kept = 0;
    if (t < NWORD) {
        sup[t] = 0ull;
        unsigned long long v = 0ull;
        for (int b = 0; b < 64; b++) {
            int r = t * 64 + b;
            if (r < NPRE && vflag[(size_t)n * NPRE + r]) v |= (1ull << b);
        }
        valw[t] = v;
    }
    __syncthreads();
    for (int i = 0; i < NPRE; ++i) {
        bool keep = ((valw[i >> 6] >> (i & 63)) & 1ull) && !((sup[i >> 6] >> (i & 63)) & 1ull);
        if (keep) {
            if (t < NWORD) sup[t] |= masks[((size_t)n * NPRE + i) * NWORD + t];
            if (t == 0) {
                int r = kept;
                if (r < NPOST) {
                    float4 b4 = ((const float4*)bsort)[(size_t)n * NPRE + i];
                    out[O_ROIS + (size_t)(n * NPOST + r) * 4 + 0] = b4.x;
                    out[O_ROIS + (size_t)(n * NPOST + r) * 4 + 1] = b4.y;
                    out[O_ROIS + (size_t)(n * NPOST + r) * 4 + 2] = b4.z;
                    out[O_ROIS + (size_t)(n * NPOST + r) * 4 + 3] = b4.w;
                    out[O_RIDX + n * NPOST + r] = (float)n;
                }
                kept = r + 1;
            }
            __syncthreads();
            if (kept >= NPOST) break;
        }
    }
    __syncthreads();
    for (int r = kept + t; r < NPOST; r += 128) {
        out[O_ROIS + (size_t)(n * NPOST + r) * 4 + 0] = 0.f;
        out[O_ROIS + (size_t)(n * NPOST + r) * 4 + 1] = 0.f;
        out[O_ROIS + (size_t)(n * NPOST + r) * 4 + 2] = 0.f;
        out[O_ROIS + (size_t)(n * NPOST + r) * 4 + 3] = 0.f;
        out[O_RIDX + n * NPOST + r] = -1.0f;
    }
}

// ---------------- anchors output ------------------------------------------------------
__global__ void k_anchor(float* __restrict__ out) {
    int i = blockIdx.x * 256 + threadIdx.x;
    if (i >= NA) return;
    int pos = i / 9, a = i - pos * 9;
    float anc[4]; anchor_for(a, pos, anc);
    out[O_ANCH + (size_t)i * 4 + 0] = anc[0];
    out[O_ANCH + (size_t)i * 4 + 1] = anc[1];
    out[O_ANCH + (size_t)i * 4 + 2] = anc[2];
    out[O_ANCH + (size_t)i * 4 + 3] = anc[3];
}

extern "C" void kernel_launch(void* const* d_in, const int* in_sizes, int n_in,
                              void* d_out, int out_size, void* d_ws, size_t ws_size,
                              hipStream_t stream) {
    const float* x   = (const float*)d_in[0];
    const float* w1  = (const float*)d_in[1];
    const float* b1  = (const float*)d_in[2];
    const float* wsc = (const float*)d_in[3];
    const float* bsc = (const float*)d_in[4];
    const float* wlc = (const float*)d_in[5];
    const float* blc = (const float*)d_in[6];
    float* out = (float*)d_out;
    char* ws = (char*)d_ws;

    float* wr2                = (float*)(ws + 0);                       //  9,437,184
    float* mid                = (float*)(ws + 9437184);                 // 67,108,864
    double* fgbuf             = (double*)(ws + 76546048);               //  2,359,296
    unsigned long long* keys  = (unsigned long long*)(ws + 78905344);   //  2,359,296
    unsigned long long* kth   = (unsigned long long*)(ws + 81264640);   //        64 (pad 512)
    unsigned int* cnt         = (unsigned int*)(ws + 81265152);         //        32 (pad 512)
    unsigned long long* cbuf  = (unsigned long long*)(ws + 81265664);   //    524,288
    float* bsort              = (float*)(ws + 81789952);                //    768,000
    unsigned char* vflag      = (unsigned char*)(ws + 82557952);        //     48,128
    unsigned long long* masks = (unsigned long long*)(ws + 82606080);   // 36,096,000 -> ~118.7MB

    hipMemsetAsync(cnt, 0, 8 * 4, stream);

    dim3 gw(64, 16);
    k_wreord<<<gw, 256, 0, stream>>>(w1, wr2);
    dim3 g3(16, 16, 8);
    k_conv3<<<g3, 256, 0, stream>>>(x, wr2, b1, mid);
    dim3 g1(64, 8);
    k_conv1<<<g1, 256, 0, stream>>>(mid, wlc, blc, wsc, bsc, out, fgbuf);
    k_keys<<<1152, 256, 0, stream>>>(out, fgbuf, keys);
    k_select<<<8, 1024, 0, stream>>>(keys, kth);
    k_compact<<<1152, 256, 0, stream>>>(keys, kth, cbuf, cnt);
    k_sort<<<8, 1024, 0, stream>>>(cbuf, out, bsort, vflag);
    dim3 gm(24, 6, 8);
    k_mask<<<gm, 256, 0, stream>>>(bsort, masks);
    k_scan<<<8, 128, 0, stream>>>(masks, vflag, bsort, out);
    k_anchor<<<144, 256, 0, stream>>>(out);
}

// Round 7
// 3443.477 us; speedup vs baseline: 1.5697x; 1.0463x over previous
//
#include <hip/hip_runtime.h>
#include <cstdint>
#include <cstddef>

#define CIN 512
#define NA 36864           // 4096 positions * 9 anchors
#define NPRE 6000
#define NPOST 300
#define CBUF_CAP 8192
#define NWORD 94           // ceil(6000/64)
#define NEGV -1000000000.0f

// d_out float offsets (return-order concat)
#define O_LOCS   0
#define O_SCORES 1179648   // 8*36864*4
#define O_ROIS   1769472   // + 8*36864*2
#define O_RIDX   1779072   // + 8*300*4
#define O_ANCH   1781472   // + 8*300

// ---------- exact-rounding helpers (ordering-critical code only) --------------------
__device__ __forceinline__ float fmulr(float a, float b) { return __fmul_rn(a, b); }
__device__ __forceinline__ float faddr(float a, float b) { return __fadd_rn(a, b); }
__device__ __forceinline__ float fsubr(float a, float b) { return __fsub_rn(a, b); }

__device__ __forceinline__ void anchor_for(int a, int pos, float* anc) {
    const double rat[3] = {0.5, 1.0, 2.0};
    const double scl[3] = {8.0, 16.0, 32.0};
    int ri = a / 3, si = a - ri * 3;
    double h = 16.0 * scl[si] * sqrt(rat[ri]);
    double w = 16.0 * scl[si] * sqrt(1.0 / rat[ri]);
    float a0 = (float)(8.0 - h * 0.5);
    float a1 = (float)(8.0 - w * 0.5);
    float a2 = (float)(8.0 + h * 0.5);
    float a3 = (float)(8.0 + w * 0.5);
    int y = pos >> 6, x = pos & 63;
    float sy = (float)(y * 16), sx = (float)(x * 16);
    anc[0] = faddr(a0, sy); anc[1] = faddr(a1, sx);
    anc[2] = faddr(a2, sy); anc[3] = faddr(a3, sx);
}

__device__ __forceinline__ bool decode_box(float4 L, const float* anc, float* box) {
    float ah  = fsubr(anc[2], anc[0]);
    float aw  = fsubr(anc[3], anc[1]);
    float acy = faddr(anc[0], fmulr(0.5f, ah));
    float acx = faddr(anc[1], fmulr(0.5f, aw));
    float cy  = faddr(fmulr(L.x, ah), acy);
    float cx  = faddr(fmulr(L.y, aw), acx);
    float h   = fmulr(ah, expf(L.z));
    float w   = fmulr(aw, expf(L.w));
    float y1 = fminf(fmaxf(fsubr(cy, fmulr(0.5f, h)), 0.0f), 1024.0f);
    float x1 = fminf(fmaxf(fsubr(cx, fmulr(0.5f, w)), 0.0f), 1024.0f);
    float y2 = fminf(fmaxf(faddr(cy, fmulr(0.5f, h)), 0.0f), 1024.0f);
    float x2 = fminf(fmaxf(faddr(cx, fmulr(0.5f, w)), 0.0f), 1024.0f);
    box[0] = y1; box[1] = x1; box[2] = y2; box[3] = x2;
    float hs = fsubr(y2, y1), ws2 = fsubr(x2, x1);
    return (hs >= 16.0f) && (ws2 >= 16.0f);
}

// monotonic 64-bit map of a double (totally ordered, sign handled)
__device__ __forceinline__ unsigned long long mono64(double f) {
    unsigned long long u = (unsigned long long)__double_as_longlong(f);
    return (u & 0x8000000000000000ull) ? ~u : (u | 0x8000000000000000ull);
}

// ---------------- weight reorder: w1[oc][c][ky][kx] -> wr2[ocb][ct(c*9+tap)][o32] ----
// LDS-tiled transpose: coalesced reads AND writes. Layout matches conv3 LDS exactly,
// so conv3's weight staging is a pure linear copy (zero address math).
__global__ __launch_bounds__(256) void k_wreord(const float* __restrict__ w1,
                                                float* __restrict__ wr2) {
    __shared__ float tile[32][73];
    const int ct0 = blockIdx.x * 72;   // 64 chunks over 4608 (c*9+tap)
    const int ocb = blockIdx.y;        // 16
    const int t = threadIdx.x;
    for (int i = t; i < 32 * 72; i += 256) {
        int orow = i / 72, ct = i - orow * 72;
        tile[orow][ct] = w1[(size_t)(ocb * 32 + orow) * 4608 + ct0 + ct];
    }
    __syncthreads();
    for (int i = t; i < 72 * 32; i += 256) {
        int ct = i >> 5, o = i & 31;
        wr2[((size_t)ocb * 4608 + ct0 + ct) * 32 + o] = tile[o][ct];
    }
}

// ---------------- 3x3 conv 512->512 + bias + relu, pure fp32 -------------------------
// block: 32 oc x 4 rows x 64 cols, 256 threads.
// Thread map: og = t>>6 (8 ocs per wave, wave-uniform -> weight LDS reads broadcast),
// tx = t&63: r = tx>>4 (row), cq = tx&15 (column quad). Per-thread 8 oc x 4 cols.
// A wave's 64 lanes read 64 DISTINCT 16B input chunks covering all 8 bank-quads
// evenly -> ds_read_b128 at the phase floor (was 4-way quad clustering by row parity).
// Summation tree per output IDENTICAL to round 5/6 (8-ch fp32 sub-chunk, cc->dy->dx
// order, fp32 merge) -> bit-identical mid.
__global__ __launch_bounds__(256, 4) void k_conv3(const float* __restrict__ x,
                                                  const float* __restrict__ wr2,
                                                  const float* __restrict__ b1,
                                                  float* __restrict__ mid) {
    __shared__ float in_s[8 * 6 * 68];   // [cc][rr(6)][xi(68)]  3264 floats
    __shared__ float w_s[8 * 9 * 32];    // [cc][tap][o32]       2304 floats
    const int yb  = blockIdx.x;          // 16
    const int ocb = blockIdx.y;          // 16
    const int n   = blockIdx.z;          // 8
    const int t   = threadIdx.x;
    const int y0  = yb * 4;
    const int og  = t >> 6;              // 0..3 -> oc group of 8 (wave-uniform)
    const int tx  = t & 63;
    const int r   = tx >> 4;             // 0..3 row
    const int cq  = tx & 15;             // 0..15 column quad (4 cols)

    float acc[8][4];
#pragma unroll
    for (int i = 0; i < 8; i++)
#pragma unroll
        for (int j = 0; j < 4; j++) acc[i][j] = 0.f;

    const size_t wblk = (size_t)ocb * 4608 * 32;
    for (int ch = 0; ch < 64; ++ch) {
        const int c0 = ch * 8;
        // weights: pure linear copy, 9 floats/thread
        const size_t wbase = wblk + (size_t)c0 * 9 * 32;
#pragma unroll
        for (int k = 0; k < 9; ++k)
            w_s[t + k * 256] = wr2[wbase + t + k * 256];
        // input tile with halo
        for (int idx = t; idx < 3264; idx += 256) {
            int cc = idx / 408, rem = idx - cc * 408;
            int rr = rem / 68, xi = rem - rr * 68;
            int gy = y0 - 1 + rr, gx = xi - 1;
            float v = 0.f;
            if (gy >= 0 && gy < 64 && xi >= 1 && xi <= 64)
                v = x[((n * CIN + c0 + cc) * 64 + gy) * 64 + gx];
            in_s[idx] = v;
        }
        __syncthreads();
        float sub[8][4];
#pragma unroll
        for (int i = 0; i < 8; i++)
#pragma unroll
            for (int j = 0; j < 4; j++) sub[i][j] = 0.f;
#pragma unroll 1
        for (int cc = 0; cc < 8; ++cc) {
#pragma unroll
            for (int dy = 0; dy < 3; ++dy) {
                const float4* ip = (const float4*)&in_s[cc * 408 + (r + dy) * 68 + cq * 4];
                float4 A = ip[0], B = ip[1];
                float in8[8] = {A.x, A.y, A.z, A.w, B.x, B.y, B.z, B.w};
#pragma unroll
                for (int dx = 0; dx < 3; ++dx) {
                    const float4* wp =
                        (const float4*)&w_s[cc * 288 + (dy * 3 + dx) * 32 + og * 8];
                    float4 W0 = wp[0], W1 = wp[1];
                    float w8[8] = {W0.x, W0.y, W0.z, W0.w, W1.x, W1.y, W1.z, W1.w};
#pragma unroll
                    for (int i = 0; i < 8; i++)
#pragma unroll
                        for (int j = 0; j < 4; j++)
                            sub[i][j] += w8[i] * in8[j + dx];
                }
            }
        }
#pragma unroll
        for (int i = 0; i < 8; i++)
#pragma unroll
            for (int j = 0; j < 4; j++) acc[i][j] += sub[i][j];
        __syncthreads();
    }
    const int ocbase = ocb * 32 + og * 8;
#pragma unroll
    for (int i = 0; i < 8; i++) {
        float bb = b1[ocbase + i];
#pragma unroll
        for (int j = 0; j < 4; j++) {
            float v = fmaxf(acc[i][j] + bb, 0.f);
            mid[((n * CIN + ocbase + i) * 64 + (y0 + r)) * 64 + cq * 4 + j] = v;
        }
    }
}

// ---------------- fused 1x1 convs (36 loc + 18 score), f64 accumulation --------------
// also computes the f64 softmax fg score per anchor into fgbuf (ordering-critical).
__global__ __launch_bounds__(256) void k_conv1(const float* __restrict__ mid,
                                               const float* __restrict__ wl,
                                               const float* __restrict__ bl,
                                               const float* __restrict__ wsc,
                                               const float* __restrict__ bs,
                                               float* __restrict__ out,
                                               double* __restrict__ fgbuf) {
    __shared__ float in_s[128 * 64];
    __shared__ float w_s[54 * 128];
    const int y = blockIdx.x;   // 64
    const int n = blockIdx.y;   // 8
    const int t = threadIdx.x;
    const int xx = t & 63, og = t >> 6;   // og uniform per wave
    double accd[14];
#pragma unroll
    for (int k = 0; k < 14; k++) accd[k] = 0.0;

    for (int c0 = 0; c0 < 512; c0 += 128) {
        for (int idx = t; idx < 128 * 64; idx += 256) {
            int cc = idx >> 6, x2 = idx & 63;
            in_s[idx] = mid[((n * CIN + c0 + cc) * 64 + y) * 64 + x2];
        }
        for (int idx = t; idx < 54 * 128; idx += 256) {
            int oc = idx >> 7, cc = idx & 127;
            w_s[idx] = (oc < 36) ? wl[oc * 512 + c0 + cc] : wsc[(oc - 36) * 512 + c0 + cc];
        }
        __syncthreads();
#pragma unroll 1
        for (int cc = 0; cc < 128; ++cc) {
            double iv = (double)in_s[cc * 64 + xx];
#pragma unroll
            for (int k = 0; k < 14; k++) {
                int oc = og * 14 + k;
                if (oc < 54) accd[k] += (double)w_s[oc * 128 + cc] * iv;
            }
        }
        __syncthreads();
    }
    const int pos = y * 64 + xx;
    double sv[14];
#pragma unroll
    for (int k = 0; k < 14; k++) {
        int oc = og * 14 + k;
        if (oc >= 54) break;
        if (oc < 36) {
            double v = accd[k] + (double)bl[oc];
            int a = oc >> 2, cd = oc & 3;
            out[O_LOCS + ((size_t)(n * NA + pos * 9 + a)) * 4 + cd] = (float)v;
        } else {
            sv[k] = accd[k] + (double)bs[oc - 36];
            int c2 = oc - 36, a = c2 >> 1, cls = c2 & 1;
            out[O_SCORES + ((size_t)(n * NA + pos * 9 + a)) * 2 + cls] = (float)sv[k];
        }
    }
#pragma unroll
    for (int k = 0; k < 13; k++) {
        int oc = og * 14 + k;
        if (oc >= 36 && oc < 54 && ((oc - 36) & 1) == 0) {
            double s0 = sv[k], s1 = sv[k + 1];
            double m = fmax(s0, s1);
            double e0 = exp(s0 - m), e1 = exp(s1 - m);
            double fg = e1 / (e0 + e1);
            int a = (oc - 36) >> 1;
            fgbuf[(size_t)n * NA + pos * 9 + a] = fg;
        }
    }
}

// ---------------- keys: mono64(f64 fg) with low 16 bits = inverted index -------------
__global__ __launch_bounds__(256) void k_keys(const float* __restrict__ out,
                                              const double* __restrict__ fgbuf,
                                              unsigned long long* __restrict__ keys) {
    const int n = blockIdx.x / 144;
    const int i = (blockIdx.x % 144) * 256 + threadIdx.x;
    int pos = i / 9, a = i - pos * 9;
    float anc[4]; anchor_for(a, pos, anc);
    float4 L = *(const float4*)&out[O_LOCS + (size_t)(n * NA + i) * 4];
    float box[4];
    bool ok = decode_box(L, anc, box);
    double f = ok ? fgbuf[(size_t)n * NA + i] : (double)NEGV;
    unsigned long long m = mono64(f);
    keys[(size_t)n * NA + i] =
        (m & 0xFFFFFFFFFFFF0000ull) | (unsigned long long)(0xFFFFu - (unsigned)i);
}

// ---------------- exact 64-bit radix select: kth[n] = 6000th largest key -------------
// 5 levels: 13+13+13+13+12 bits. Keys unique -> count(key >= kth) == 6000 exactly.
__global__ __launch_bounds__(1024) void k_select(const unsigned long long* __restrict__ keys,
                                                 unsigned long long* __restrict__ kth) {
    __shared__ unsigned int hist[8192];
    __shared__ unsigned int gs[256];
    __shared__ unsigned long long s_pref;
    __shared__ int s_plen, s_rem;
    const int n = blockIdx.x, t = threadIdx.x;
    if (t == 0) { s_pref = 0ull; s_plen = 0; s_rem = NPRE; }
    __syncthreads();
    const int shifts[5] = {51, 38, 25, 12, 0};
    const int widths[5] = {13, 13, 13, 13, 12};
    for (int lev = 0; lev < 5; ++lev) {
        const int nb = 1 << widths[lev];
        for (int b = t; b < nb; b += 1024) hist[b] = 0;
        __syncthreads();
        const unsigned long long pref = s_pref;
        const int plen = s_plen;
        for (int i = t; i < NA; i += 1024) {
            unsigned long long key = keys[(size_t)n * NA + i];
            if (plen == 0 || (key >> (64 - plen)) == pref) {
                unsigned int bin = (unsigned int)((key >> shifts[lev]) & (unsigned)(nb - 1));
                atomicAdd(&hist[bin], 1u);
            }
        }
        __syncthreads();
        const int gsz = nb >> 8;   // bins per thread-group
        if (t < 256) {
            unsigned int s = 0;
            for (int m = 0; m < gsz; m++) s += hist[t * gsz + m];
            gs[t] = s;
        }
        __syncthreads();
        if (t == 0) {
            const unsigned int rem = (unsigned int)s_rem;
            unsigned int acc = 0; int selbin = 0;
            for (int g = 255; g >= 0; --g) {
                if (acc + gs[g] >= rem) {
                    for (int b = g * gsz + gsz - 1; b >= g * gsz; --b) {
                        if (acc + hist[b] >= rem) { selbin = b; break; }
                        acc += hist[b];
                    }
                    break;
                }
                acc += gs[g];
            }
            s_rem = (int)(rem - acc);
            s_pref = (s_pref << widths[lev]) | (unsigned long long)(unsigned)selbin;
            s_plen += widths[lev];
        }
        __syncthreads();
    }
    if (t == 0) kth[n] = s_pref;
}

// ---------------- compact: exactly the 6000 keys >= kth ------------------------------
__global__ void k_compact(const unsigned long long* __restrict__ keys,
                          const unsigned long long* __restrict__ kth,
                          unsigned long long* __restrict__ cbuf,
                          unsigned int* __restrict__ cnt) {
    const int n = blockIdx.x / 144;
    const int i = (blockIdx.x % 144) * 256 + threadIdx.x;
    unsigned long long key = keys[(size_t)n * NA + i];
    if (key >= kth[n]) {
        unsigned int p = atomicAdd(&cnt[n], 1u);
        if (p < CBUF_CAP) cbuf[(size_t)n * CBUF_CAP + p] = key;
    }
}

// ---------------- per-image LDS bitonic sort (descending), emit top-6000 boxes -------
__global__ __launch_bounds__(1024) void k_sort(const unsigned long long* __restrict__ cbuf,
                                               const float* __restrict__ out,
                                               float* __restrict__ bsort,
                                               unsigned char* __restrict__ vflag) {
    __shared__ unsigned long long arr[CBUF_CAP];
    const int n = blockIdx.x, t = threadIdx.x;
    for (int idx = t; idx < CBUF_CAP; idx += 1024)
        arr[idx] = (idx < NPRE) ? cbuf[(size_t)n * CBUF_CAP + idx] : 0ull;
    __syncthreads();
    for (int k = 2; k <= CBUF_CAP; k <<= 1)
        for (int j = k >> 1; j > 0; j >>= 1) {
            for (int i = t; i < CBUF_CAP; i += 1024) {
                int ixj = i ^ j;
                if (ixj > i) {
                    unsigned long long a = arr[i], b = arr[ixj];
                    bool up = (i & k) == 0;
                    if (up ? (a < b) : (a > b)) { arr[i] = b; arr[ixj] = a; }
                }
            }
            __syncthreads();
        }
    for (int r = t; r < NPRE; r += 1024) {
        unsigned long long key = arr[r];
        unsigned int i = 0xFFFFu - (unsigned int)(key & 0xFFFFull);
        int pos = i / 9, a = i - pos * 9;
        float anc[4]; anchor_for(a, pos, anc);
        float4 L = *(const float4*)&out[O_LOCS + (size_t)(n * NA + i) * 4];
        float box[4];
        bool ok = decode_box(L, anc, box);
        ((float4*)bsort)[(size_t)n * NPRE + r] = make_float4(box[0], box[1], box[2], box[3]);
        vflag[(size_t)n * NPRE + r] = ok ? 1 : 0;
    }
}

// ---------------- suppression bitmask matrix (bits j>i with IoU>0.7) -----------------
// grid (24 i-chunks, 6 j-chunks, 8 n): 1152 blocks for latency hiding.
__global__ __launch_bounds__(256) void k_mask(const float* __restrict__ bsort,
                                              unsigned long long* __restrict__ masks) {
    __shared__ float4 bx[1024];
    const int n  = blockIdx.z;
    const int jc = blockIdx.y;
    const int i  = blockIdx.x * 256 + threadIdx.x;
    const bool have = i < NPRE;
    float4 bi = make_float4(0, 0, 0, 0); float areai = 0.f;
    if (have) {
        bi = ((const float4*)bsort)[(size_t)n * NPRE + i];
        areai = fmulr(fsubr(bi.z, bi.x), fsubr(bi.w, bi.y));
    }
    const int jn = min(1024, NPRE - jc * 1024);
    for (int jj = threadIdx.x; jj < jn; jj += 256)
        bx[jj] = ((const float4*)bsort)[(size_t)n * NPRE + jc * 1024 + jj];
    __syncthreads();
    for (int w = 0; w < 16; ++w) {
        int gw = jc * 16 + w;
        if (gw >= NWORD) break;
        unsigned long long m = 0ull;
        int jbase = jc * 1024 + w * 64;
        if (have && jbase + 63 > i) {
#pragma unroll 1
            for (int b = 0; b < 64; b++) {
                int j = jbase + b;
                if (j > i && j < NPRE) {
                    float4 bj = bx[w * 64 + b];
                    float ih = fmaxf(fsubr(fminf(bi.z, bj.z), fmaxf(bi.x, bj.x)), 0.f);
                    float iw = fmaxf(fsubr(fminf(bi.w, bj.w), fmaxf(bi.y, bj.y)), 0.f);
                    float inter = fmulr(ih, iw);
                    float areaj = fmulr(fsubr(bj.z, bj.x), fsubr(bj.w, bj.y));
                    float den = faddr(fsubr(faddr(areai, areaj), inter), 1e-9f);
                    float iou = __fdiv_rn(inter, den);
                    if (iou > 0.7f) m |= (1ull << b);
                }
            }
        }
        if (have) masks[((size_t)n * NPRE + i) * NWORD + gw] = m;
    }
}

// ---------------- serial greedy scan with early exit at 300 kept ---------------------
__global__ __launch_bounds__(128) void k_scan(const unsigned long long* __restrict__ masks,
                                              const unsigned char* __restrict__ vflag,
                                              const float* __restrict__ bsort,
                                              float* __restrict__ out) {
    __shared__ unsigned long long sup[NWORD];
    __shared__ unsigned long long valw[NWORD];
    __shared__ int kept;
    const int n = blockIdx.x, t = threadIdx.x;
    if (t == 0) kept = 0;
    if (t < NWORD) {
        sup[t] = 0ull;
        unsigned long long v = 0ull;
        for (int b = 0; b < 64; b++) {
            int r = t * 64 + b;
            if (r < NPRE && vflag[(size_t)n * NPRE + r]) v |= (1ull << b);
        }
        valw[t] = v;
    }
    __syncthreads();
    for (int i = 0; i < NPRE; ++i) {
        bool keep = ((valw[i >> 6] >> (i & 63)) & 1ull) && !((sup[i >> 6] >> (i & 63)) & 1ull);
        if (keep) {
            if (t < NWORD) sup[t] |= masks[((size_t)n * NPRE + i) * NWORD + t];
            if (t == 0) {
                int r = kept;
                if (r < NPOST) {
                    float4 b4 = ((const float4*)bsort)[(size_t)n * NPRE + i];
                    out[O_ROIS + (size_t)(n * NPOST + r) * 4 + 0] = b4.x;
                    out[O_ROIS + (size_t)(n * NPOST + r) * 4 + 1] = b4.y;
                    out[O_ROIS + (size_t)(n * NPOST + r) * 4 + 2] = b4.z;
                    out[O_ROIS + (size_t)(n * NPOST + r) * 4 + 3] = b4.w;
                    out[O_RIDX + n * NPOST + r] = (float)n;
                }
                kept = r + 1;
            }
            __syncthreads();
            if (kept >= NPOST) break;
        }
    }
    __syncthreads();
    for (int r = kept + t; r < NPOST; r += 128) {
        out[O_ROIS + (size_t)(n * NPOST + r) * 4 + 0] = 0.f;
        out[O_ROIS + (size_t)(n * NPOST + r) * 4 + 1] = 0.f;
        out[O_ROIS + (size_t)(n * NPOST + r) * 4 + 2] = 0.f;
        out[O_ROIS + (size_t)(n * NPOST + r) * 4 + 3] = 0.f;
        out[O_RIDX + n * NPOST + r] = -1.0f;
    }
}

// ---------------- anchors output ------------------------------------------------------
__global__ void k_anchor(float* __restrict__ out) {
    int i = blockIdx.x * 256 + threadIdx.x;
    if (i >= NA) return;
    int pos = i / 9, a = i - pos * 9;
    float anc[4]; anchor_for(a, pos, anc);
    out[O_ANCH + (size_t)i * 4 + 0] = anc[0];
    out[O_ANCH + (size_t)i * 4 + 1] = anc[1];
    out[O_ANCH + (size_t)i * 4 + 2] = anc[2];
    out[O_ANCH + (size_t)i * 4 + 3] = anc[3];
}

extern "C" void kernel_launch(void* const* d_in, const int* in_sizes, int n_in,
                              void* d_out, int out_size, void* d_ws, size_t ws_size,
                              hipStream_t stream) {
    const float* x   = (const float*)d_in[0];
    const float* w1  = (const float*)d_in[1];
    const float* b1  = (const float*)d_in[2];
    const float* wsc = (const float*)d_in[3];
    const float* bsc = (const float*)d_in[4];
    const float* wlc = (const float*)d_in[5];
    const float* blc = (const float*)d_in[6];
    float* out = (float*)d_out;
    char* ws = (char*)d_ws;

    float* wr2                = (float*)(ws + 0);                       //  9,437,184
    float* mid                = (float*)(ws + 9437184);                 // 67,108,864
    double* fgbuf             = (double*)(ws + 76546048);               //  2,359,296
    unsigned long long* keys  = (unsigned long long*)(ws + 78905344);   //  2,359,296
    unsigned long long* kth   = (unsigned long long*)(ws + 81264640);   //        64 (pad 512)
    unsigned int* cnt         = (unsigned int*)(ws + 81265152);         //        32 (pad 512)
    unsigned long long* cbuf  = (unsigned long long*)(ws + 81265664);   //    524,288
    float* bsort              = (float*)(ws + 81789952);                //    768,000
    unsigned char* vflag      = (unsigned char*)(ws + 82557952);        //     48,128
    unsigned long long* masks = (unsigned long long*)(ws + 82606080);   // 36,096,000 -> ~118.7MB

    hipMemsetAsync(cnt, 0, 8 * 4, stream);

    dim3 gw(64, 16);
    k_wreord<<<gw, 256, 0, stream>>>(w1, wr2);
    dim3 g3(16, 16, 8);
    k_conv3<<<g3, 256, 0, stream>>>(x, wr2, b1, mid);
    dim3 g1(64, 8);
    k_conv1<<<g1, 256, 0, stream>>>(mid, wlc, blc, wsc, bsc, out, fgbuf);
    k_keys<<<1152, 256, 0, stream>>>(out, fgbuf, keys);
    k_select<<<8, 1024, 0, stream>>>(keys, kth);
    k_compact<<<1152, 256, 0, stream>>>(keys, kth, cbuf, cnt);
    k_sort<<<8, 1024, 0, stream>>>(cbuf, out, bsort, vflag);
    dim3 gm(24, 6, 8);
    k_mask<<<gm, 256, 0, stream>>>(bsort, masks);
    k_scan<<<8, 128, 0, stream>>>(masks, vflag, bsort, out);
    k_anchor<<<144, 256, 0, stream>>>(out);
}

// Round 8
// 2998.157 us; speedup vs baseline: 1.8028x; 1.1485x over previous
//
#include <hip/hip_runtime.h>
#include <cstdint>
#include <cstddef>

#define CIN 512
#define NA 36864           // 4096 positions * 9 anchors
#define NPRE 6000
#define NPOST 300
#define CBUF_CAP 8192
#define NWORD 94           // ceil(6000/64)
#define NEGV -1000000000.0f
#define ISTRIDE 76         // input LDS row stride (odd*4 floats -> bank spread)

// d_out float offsets (return-order concat)
#define O_LOCS   0
#define O_SCORES 1179648   // 8*36864*4
#define O_ROIS   1769472   // + 8*36864*2
#define O_RIDX   1779072   // + 8*300*4
#define O_ANCH   1781472   // + 8*300

// ---------- exact-rounding helpers (ordering-critical code only) --------------------
__device__ __forceinline__ float fmulr(float a, float b) { return __fmul_rn(a, b); }
__device__ __forceinline__ float faddr(float a, float b) { return __fadd_rn(a, b); }
__device__ __forceinline__ float fsubr(float a, float b) { return __fsub_rn(a, b); }

__device__ __forceinline__ void anchor_for(int a, int pos, float* anc) {
    const double rat[3] = {0.5, 1.0, 2.0};
    const double scl[3] = {8.0, 16.0, 32.0};
    int ri = a / 3, si = a - ri * 3;
    double h = 16.0 * scl[si] * sqrt(rat[ri]);
    double w = 16.0 * scl[si] * sqrt(1.0 / rat[ri]);
    float a0 = (float)(8.0 - h * 0.5);
    float a1 = (float)(8.0 - w * 0.5);
    float a2 = (float)(8.0 + h * 0.5);
    float a3 = (float)(8.0 + w * 0.5);
    int y = pos >> 6, x = pos & 63;
    float sy = (float)(y * 16), sx = (float)(x * 16);
    anc[0] = faddr(a0, sy); anc[1] = faddr(a1, sx);
    anc[2] = faddr(a2, sy); anc[3] = faddr(a3, sx);
}

__device__ __forceinline__ bool decode_box(float4 L, const float* anc, float* box) {
    float ah  = fsubr(anc[2], anc[0]);
    float aw  = fsubr(anc[3], anc[1]);
    float acy = faddr(anc[0], fmulr(0.5f, ah));
    float acx = faddr(anc[1], fmulr(0.5f, aw));
    float cy  = faddr(fmulr(L.x, ah), acy);
    float cx  = faddr(fmulr(L.y, aw), acx);
    float h   = fmulr(ah, expf(L.z));
    float w   = fmulr(aw, expf(L.w));
    float y1 = fminf(fmaxf(fsubr(cy, fmulr(0.5f, h)), 0.0f), 1024.0f);
    float x1 = fminf(fmaxf(fsubr(cx, fmulr(0.5f, w)), 0.0f), 1024.0f);
    float y2 = fminf(fmaxf(faddr(cy, fmulr(0.5f, h)), 0.0f), 1024.0f);
    float x2 = fminf(fmaxf(faddr(cx, fmulr(0.5f, w)), 0.0f), 1024.0f);
    box[0] = y1; box[1] = x1; box[2] = y2; box[3] = x2;
    float hs = fsubr(y2, y1), ws2 = fsubr(x2, x1);
    return (hs >= 16.0f) && (ws2 >= 16.0f);
}

// monotonic 64-bit map of a double (totally ordered, sign handled)
__device__ __forceinline__ unsigned long long mono64(double f) {
    unsigned long long u = (unsigned long long)__double_as_longlong(f);
    return (u & 0x8000000000000000ull) ? ~u : (u | 0x8000000000000000ull);
}

// ---------------- weight reorder: w1[oc][c][ky][kx] -> wr2[ocb64][ct(c*9+tap)][o64] --
// LDS-tiled transpose. Output layout is exactly conv3's LDS order per 64-oc block,
// so conv3 weight staging is a pure linear float4 copy.
__global__ __launch_bounds__(256) void k_wreord(const float* __restrict__ w1,
                                                float* __restrict__ wr2) {
    __shared__ float tile[64][37];
    const int ct0 = blockIdx.x * 36;   // 128 chunks over 4608
    const int ocb = blockIdx.y;        // 8
    const int t = threadIdx.x;
    for (int i = t; i < 64 * 36; i += 256) {
        int orow = i / 36, c = i - orow * 36;
        tile[orow][c] = w1[(size_t)(ocb * 64 + orow) * 4608 + ct0 + c];
    }
    __syncthreads();
    for (int i = t; i < 36 * 64; i += 256) {
        int ct = i >> 6, o = i & 63;
        wr2[((size_t)ocb * 4608 + ct0 + ct) * 64 + o] = tile[o][ct];
    }
}

// ---------------- 3x3 conv 512->512 + bias + relu, pure fp32 -------------------------
// block: 64 oc x 4 rows x 64 cols, 256 threads; per-thread 8 oc x 8 cols.
// Summation tree per output IDENTICAL to rounds 5-7 (8-ch fp32 sub-chunk, cc->dy->dx
// order, fp32 merge into acc) -> bit-identical mid.
// Staging: fully hoisted aligned float4 copies (no divisions in the ch loop).
// Input LDS rows: [4 zero-pad][gx 0..63][pad], stride 76 -> aligned reads/writes and
// odd-quad bank spread. LDS reads per cc: 12 input b128 (distinct) + 18 weight b128
// (half-wave broadcast) for 576 FMA -> FMA-bound.
__global__ __launch_bounds__(256, 2) void k_conv3(const float* __restrict__ x,
                                                  const float* __restrict__ wr2,
                                                  const float* __restrict__ b1,
                                                  float* __restrict__ mid) {
    __shared__ float in_s[8 * 6 * ISTRIDE];   // 3648 floats
    __shared__ float w_s[8 * 9 * 64];         // 4608 floats
    const int yb  = blockIdx.x;          // 16
    const int ocb = blockIdx.y;          // 8
    const int n   = blockIdx.z;          // 8
    const int t   = threadIdx.x;
    const int y0  = yb * 4;
    const int tocg = t >> 5;             // 0..7 -> oc group of 8
    const int tx   = t & 31;
    const int r    = tx >> 3;            // 0..3 row
    const int xo   = (tx & 7) << 3;      // 0..56 col octet

    // zero halo pads once: xi 0..3 and 68..71 on all 48 rows (never overwritten)
    for (int i = t; i < 48 * 8; i += 256) {
        int row = i >> 3, c = i & 7;
        int xi = (c < 4) ? c : 64 + c;   // 0..3, 68..71
        in_s[row * ISTRIDE + xi] = 0.f;
    }

    // hoisted input staging: 768 f4 slots (48 rows x 16), thread -> slots t,t+256,t+512
    int   ilds[3];
    int   ival[3];
    const float* igp[3];
#pragma unroll
    for (int k = 0; k < 3; ++k) {
        int s = t + k * 256;
        int row = s >> 4, col = s & 15;
        int cc = row / 6, rr = row - cc * 6;
        int gy = y0 - 1 + rr;
        ival[k] = (gy >= 0 && gy < 64) ? 1 : 0;
        int gyc = min(max(gy, 0), 63);
        ilds[k] = row * ISTRIDE + 4 + col * 4;
        igp[k]  = x + (((size_t)(n * CIN + cc) * 64 + gyc) * 64 + col * 4);
    }
    const float* wgp = wr2 + (size_t)ocb * (4608 * 64);

    float acc[8][8];
#pragma unroll
    for (int i = 0; i < 8; i++)
#pragma unroll
        for (int j = 0; j < 8; j++) acc[i][j] = 0.f;

    for (int ch = 0; ch < 64; ++ch) {
        // ---- stage weights: linear float4 copy of 4608 floats ----
        const float* wp0 = wgp + (size_t)ch * 4608;
#pragma unroll
        for (int k = 0; k < 4; ++k)
            *(float4*)&w_s[4 * t + 1024 * k] = *(const float4*)(wp0 + 4 * t + 1024 * k);
        if (t < 128)
            *(float4*)&w_s[4 * t + 4096] = *(const float4*)(wp0 + 4 * t + 4096);
        // ---- stage input: 3 aligned float4 per thread, precomputed addresses ----
#pragma unroll
        for (int k = 0; k < 3; ++k) {
            float4 v = make_float4(0.f, 0.f, 0.f, 0.f);
            if (ival[k]) v = *(const float4*)(igp[k] + (size_t)ch * 32768);
            *(float4*)&in_s[ilds[k]] = v;
        }
        __syncthreads();

        float sub[8][8];
#pragma unroll
        for (int i = 0; i < 8; i++)
#pragma unroll
            for (int j = 0; j < 8; j++) sub[i][j] = 0.f;
#pragma unroll 1
        for (int cc = 0; cc < 8; ++cc) {
#pragma unroll
            for (int dy = 0; dy < 3; ++dy) {
                const float4* ip =
                    (const float4*)&in_s[cc * (6 * ISTRIDE) + (r + dy) * ISTRIDE + xo];
                float4 Q0 = ip[0], Q1 = ip[1], Q2 = ip[2], Q3 = ip[3];
                float in16[16] = {Q0.x, Q0.y, Q0.z, Q0.w, Q1.x, Q1.y, Q1.z, Q1.w,
                                  Q2.x, Q2.y, Q2.z, Q2.w, Q3.x, Q3.y, Q3.z, Q3.w};
#pragma unroll
                for (int dx = 0; dx < 3; ++dx) {
                    const float4* wp =
                        (const float4*)&w_s[cc * 576 + (dy * 3 + dx) * 64 + tocg * 8];
                    float4 W0 = wp[0], W1 = wp[1];
                    float w8[8] = {W0.x, W0.y, W0.z, W0.w, W1.x, W1.y, W1.z, W1.w};
#pragma unroll
                    for (int i = 0; i < 8; i++)
#pragma unroll
                        for (int j = 0; j < 8; j++)
                            sub[i][j] += w8[i] * in16[j + dx + 3];
                }
            }
        }
#pragma unroll
        for (int i = 0; i < 8; i++)
#pragma unroll
            for (int j = 0; j < 8; j++) acc[i][j] += sub[i][j];
        __syncthreads();
    }
    const int ocbase = (ocb << 6) + tocg * 8;
#pragma unroll
    for (int i = 0; i < 8; i++) {
        float bb = b1[ocbase + i];
#pragma unroll
        for (int j = 0; j < 8; j++) {
            float v = fmaxf(acc[i][j] + bb, 0.f);
            mid[((n * CIN + ocbase + i) * 64 + (y0 + r)) * 64 + xo + j] = v;
        }
    }
}

// ---------------- fused 1x1 convs (36 loc + 18 score), f64 accumulation --------------
// also computes the f64 softmax fg score per anchor into fgbuf (ordering-critical).
__global__ __launch_bounds__(256) void k_conv1(const float* __restrict__ mid,
                                               const float* __restrict__ wl,
                                               const float* __restrict__ bl,
                                               const float* __restrict__ wsc,
                                               const float* __restrict__ bs,
                                               float* __restrict__ out,
                                               double* __restrict__ fgbuf) {
    __shared__ float in_s[128 * 64];
    __shared__ float w_s[54 * 128];
    const int y = blockIdx.x;   // 64
    const int n = blockIdx.y;   // 8
    const int t = threadIdx.x;
    const int xx = t & 63, og = t >> 6;   // og uniform per wave
    double accd[14];
#pragma unroll
    for (int k = 0; k < 14; k++) accd[k] = 0.0;

    for (int c0 = 0; c0 < 512; c0 += 128) {
        for (int idx = t; idx < 128 * 64; idx += 256) {
            int cc = idx >> 6, x2 = idx & 63;
            in_s[idx] = mid[((n * CIN + c0 + cc) * 64 + y) * 64 + x2];
        }
        for (int idx = t; idx < 54 * 128; idx += 256) {
            int oc = idx >> 7, cc = idx & 127;
            w_s[idx] = (oc < 36) ? wl[oc * 512 + c0 + cc] : wsc[(oc - 36) * 512 + c0 + cc];
        }
        __syncthreads();
#pragma unroll 1
        for (int cc = 0; cc < 128; ++cc) {
            double iv = (double)in_s[cc * 64 + xx];
#pragma unroll
            for (int k = 0; k < 14; k++) {
                int oc = og * 14 + k;
                if (oc < 54) accd[k] += (double)w_s[oc * 128 + cc] * iv;
            }
        }
        __syncthreads();
    }
    const int pos = y * 64 + xx;
    double sv[14];
#pragma unroll
    for (int k = 0; k < 14; k++) {
        int oc = og * 14 + k;
        if (oc >= 54) break;
        if (oc < 36) {
            double v = accd[k] + (double)bl[oc];
            int a = oc >> 2, cd = oc & 3;
            out[O_LOCS + ((size_t)(n * NA + pos * 9 + a)) * 4 + cd] = (float)v;
        } else {
            sv[k] = accd[k] + (double)bs[oc - 36];
            int c2 = oc - 36, a = c2 >> 1, cls = c2 & 1;
            out[O_SCORES + ((size_t)(n * NA + pos * 9 + a)) * 2 + cls] = (float)sv[k];
        }
    }
#pragma unroll
    for (int k = 0; k < 13; k++) {
        int oc = og * 14 + k;
        if (oc >= 36 && oc < 54 && ((oc - 36) & 1) == 0) {
            double s0 = sv[k], s1 = sv[k + 1];
            double m = fmax(s0, s1);
            double e0 = exp(s0 - m), e1 = exp(s1 - m);
            double fg = e1 / (e0 + e1);
            int a = (oc - 36) >> 1;
            fgbuf[(size_t)n * NA + pos * 9 + a] = fg;
        }
    }
}

// ---------------- keys: mono64(f64 fg) with low 16 bits = inverted index -------------
__global__ __launch_bounds__(256) void k_keys(const float* __restrict__ out,
                                              const double* __restrict__ fgbuf,
                                              unsigned long long* __restrict__ keys) {
    const int n = blockIdx.x / 144;
    const int i = (blockIdx.x % 144) * 256 + threadIdx.x;
    int pos = i / 9, a = i - pos * 9;
    float anc[4]; anchor_for(a, pos, anc);
    float4 L = *(const float4*)&out[O_LOCS + (size_t)(n * NA + i) * 4];
    float box[4];
    bool ok = decode_box(L, anc, box);
    double f = ok ? fgbuf[(size_t)n * NA + i] : (double)NEGV;
    unsigned long long m = mono64(f);
    keys[(size_t)n * NA + i] =
        (m & 0xFFFFFFFFFFFF0000ull) | (unsigned long long)(0xFFFFu - (unsigned)i);
}

// ---------------- exact 64-bit radix select: kth[n] = 6000th largest key -------------
// 5 levels: 13+13+13+13+12 bits. Keys unique -> count(key >= kth) == 6000 exactly.
__global__ __launch_bounds__(1024) void k_select(const unsigned long long* __restrict__ keys,
                                                 unsigned long long* __restrict__ kth) {
    __shared__ unsigned int hist[8192];
    __shared__ unsigned int gs[256];
    __shared__ unsigned long long s_pref;
    __shared__ int s_plen, s_rem;
    const int n = blockIdx.x, t = threadIdx.x;
    if (t == 0) { s_pref = 0ull; s_plen = 0; s_rem = NPRE; }
    __syncthreads();
    const int shifts[5] = {51, 38, 25, 12, 0};
    const int widths[5] = {13, 13, 13, 13, 12};
    for (int lev = 0; lev < 5; ++lev) {
        const int nb = 1 << widths[lev];
        for (int b = t; b < nb; b += 1024) hist[b] = 0;
        __syncthreads();
        const unsigned long long pref = s_pref;
        const int plen = s_plen;
        for (int i = t; i < NA; i += 1024) {
            unsigned long long key = keys[(size_t)n * NA + i];
            if (plen == 0 || (key >> (64 - plen)) == pref) {
                unsigned int bin = (unsigned int)((key >> shifts[lev]) & (unsigned)(nb - 1));
                atomicAdd(&hist[bin], 1u);
            }
        }
        __syncthreads();
        const int gsz = nb >> 8;   // bins per thread-group
        if (t < 256) {
            unsigned int s = 0;
            for (int m = 0; m < gsz; m++) s += hist[t * gsz + m];
            gs[t] = s;
        }
        __syncthreads();
        if (t == 0) {
            const unsigned int rem = (unsigned int)s_rem;
            unsigned int acc = 0; int selbin = 0;
            for (int g = 255; g >= 0; --g) {
                if (acc + gs[g] >= rem) {
                    for (int b = g * gsz + gsz - 1; b >= g * gsz; --b) {
                        if (acc + hist[b] >= rem) { selbin = b; break; }
                        acc += hist[b];
                    }
                    break;
                }
                acc += gs[g];
            }
            s_rem = (int)(rem - acc);
            s_pref = (s_pref << widths[lev]) | (unsigned long long)(unsigned)selbin;
            s_plen += widths[lev];
        }
        __syncthreads();
    }
    if (t == 0) kth[n] = s_pref;
}

// ---------------- compact: exactly the 6000 keys >= kth ------------------------------
__global__ void k_compact(const unsigned long long* __restrict__ keys,
                          const unsigned long long* __restrict__ kth,
                          unsigned long long* __restrict__ cbuf,
                          unsigned int* __restrict__ cnt) {
    const int n = blockIdx.x / 144;
    const int i = (blockIdx.x % 144) * 256 + threadIdx.x;
    unsigned long long key = keys[(size_t)n * NA + i];
    if (key >= kth[n]) {
        unsigned int p = atomicAdd(&cnt[n], 1u);
        if (p < CBUF_CAP) cbuf[(size_t)n * CBUF_CAP + p] = key;
    }
}

// ---------------- per-image LDS bitonic sort (descending), emit top-6000 boxes -------
__global__ __launch_bounds__(1024) void k_sort(const unsigned long long* __restrict__ cbuf,
                                               const float* __restrict__ out,
                                               float* __restrict__ bsort,
                                               unsigned char* __restrict__ vflag) {
    __shared__ unsigned long long arr[CBUF_CAP];
    const int n = blockIdx.x, t = threadIdx.x;
    for (int idx = t; idx < CBUF_CAP; idx += 1024)
        arr[idx] = (idx < NPRE) ? cbuf[(size_t)n * CBUF_CAP + idx] : 0ull;
    __syncthreads();
    for (int k = 2; k <= CBUF_CAP; k <<= 1)
        for (int j = k >> 1; j > 0; j >>= 1) {
            for (int i = t; i < CBUF_CAP; i += 1024) {
                int ixj = i ^ j;
                if (ixj > i) {
                    unsigned long long a = arr[i], b = arr[ixj];
                    bool up = (i & k) == 0;
                    if (up ? (a < b) : (a > b)) { arr[i] = b; arr[ixj] = a; }
                }
            }
            __syncthreads();
        }
    for (int r = t; r < NPRE; r += 1024) {
        unsigned long long key = arr[r];
        unsigned int i = 0xFFFFu - (unsigned int)(key & 0xFFFFull);
        int pos = i / 9, a = i - pos * 9;
        float anc[4]; anchor_for(a, pos, anc);
        float4 L = *(const float4*)&out[O_LOCS + (size_t)(n * NA + i) * 4];
        float box[4];
        bool ok = decode_box(L, anc, box);
        ((float4*)bsort)[(size_t)n * NPRE + r] = make_float4(box[0], box[1], box[2], box[3]);
        vflag[(size_t)n * NPRE + r] = ok ? 1 : 0;
    }
}

// ---------------- suppression bitmask matrix (bits j>i with IoU>0.7) -----------------
// grid (24 i-chunks, 6 j-chunks, 8 n): 1152 blocks for latency hiding.
__global__ __launch_bounds__(256) void k_mask(const float* __restrict__ bsort,
                                              unsigned long long* __restrict__ masks) {
    __shared__ float4 bx[1024];
    const int n  = blockIdx.z;
    const int jc = blockIdx.y;
    const int i  = blockIdx.x * 256 + threadIdx.x;
    const bool have = i < NPRE;
    float4 bi = make_float4(0, 0, 0, 0); float areai = 0.f;
    if (have) {
        bi = ((const float4*)bsort)[(size_t)n * NPRE + i];
        areai = fmulr(fsubr(bi.z, bi.x), fsubr(bi.w, bi.y));
    }
    const int jn = min(1024, NPRE - jc * 1024);
    for (int jj = threadIdx.x; jj < jn; jj += 256)
        bx[jj] = ((const float4*)bsort)[(size_t)n * NPRE + jc * 1024 + jj];
    __syncthreads();
    for (int w = 0; w < 16; ++w) {
        int gw = jc * 16 + w;
        if (gw >= NWORD) break;
        unsigned long long m = 0ull;
        int jbase = jc * 1024 + w * 64;
        if (have && jbase + 63 > i) {
#pragma unroll 1
            for (int b = 0; b < 64; b++) {
                int j = jbase + b;
                if (j > i && j < NPRE) {
                    float4 bj = bx[w * 64 + b];
                    float ih = fmaxf(fsubr(fminf(bi.z, bj.z), fmaxf(bi.x, bj.x)), 0.f);
                    float iw = fmaxf(fsubr(fminf(bi.w, bj.w), fmaxf(bi.y, bj.y)), 0.f);
                    float inter = fmulr(ih, iw);
                    float areaj = fmulr(fsubr(bj.z, bj.x), fsubr(bj.w, bj.y));
                    float den = faddr(fsubr(faddr(areai, areaj), inter), 1e-9f);
                    float iou = __fdiv_rn(inter, den);
                    if (iou > 0.7f) m |= (1ull << b);
                }
            }
        }
        if (have) masks[((size_t)n * NPRE + i) * NWORD + gw] = m;
    }
}

// ---------------- serial greedy scan with early exit at 300 kept ---------------------
__global__ __launch_bounds__(128) void k_scan(const unsigned long long* __restrict__ masks,
                                              const unsigned char* __restrict__ vflag,
                                              const float* __restrict__ bsort,
                                              float* __restrict__ out) {
    __shared__ unsigned long long sup[NWORD];
    __shared__ unsigned long long valw[NWORD];
    __shared__ int kept;
    const int n = blockIdx.x, t = threadIdx.x;
    if (t == 0) kept = 0;
    if (t < NWORD) {
        sup[t] = 0ull;
        unsigned long long v = 0ull;
        for (int b = 0; b < 64; b++) {
            int r = t * 64 + b;
            if (r < NPRE && vflag[(size_t)n * NPRE + r]) v |= (1ull << b);
        }
        valw[t] = v;
    }
    __syncthreads();
    for (int i = 0; i < NPRE; ++i) {
        bool keep = ((valw[i >> 6] >> (i & 63)) & 1ull) && !((sup[i >> 6] >> (i & 63)) & 1ull);
        if (keep) {
            if (t < NWORD) sup[t] |= masks[((size_t)n * NPRE + i) * NWORD + t];
            if (t == 0) {
                int r = kept;
                if (r < NPOST) {
                    float4 b4 = ((const float4*)bsort)[(size_t)n * NPRE + i];
                    out[O_ROIS + (size_t)(n * NPOST + r) * 4 + 0] = b4.x;
                    out[O_ROIS + (size_t)(n * NPOST + r) * 4 + 1] = b4.y;
                    out[O_ROIS + (size_t)(n * NPOST + r) * 4 + 2] = b4.z;
                    out[O_ROIS + (size_t)(n * NPOST + r) * 4 + 3] = b4.w;
                    out[O_RIDX + n * NPOST + r] = (float)n;
                }
                kept = r + 1;
            }
            __syncthreads();
            if (kept >= NPOST) break;
        }
    }
    __syncthreads();
    for (int r = kept + t; r < NPOST; r += 128) {
        out[O_ROIS + (size_t)(n * NPOST + r) * 4 + 0] = 0.f;
        out[O_ROIS + (size_t)(n * NPOST + r) * 4 + 1] = 0.f;
        out[O_ROIS + (size_t)(n * NPOST + r) * 4 + 2] = 0.f;
        out[O_ROIS + (size_t)(n * NPOST + r) * 4 + 3] = 0.f;
        out[O_RIDX + n * NPOST + r] = -1.0f;
    }
}

// ---------------- anchors output ------------------------------------------------------
__global__ void k_anchor(float* __restrict__ out) {
    int i = blockIdx.x * 256 + threadIdx.x;
    if (i >= NA) return;
    int pos = i / 9, a = i - pos * 9;
    float anc[4]; anchor_for(a, pos, anc);
    out[O_ANCH + (size_t)i * 4 + 0] = anc[0];
    out[O_ANCH + (size_t)i * 4 + 1] = anc[1];
    out[O_ANCH + (size_t)i * 4 + 2] = anc[2];
    out[O_ANCH + (size_t)i * 4 + 3] = anc[3];
}

extern "C" void kernel_launch(void* const* d_in, const int* in_sizes, int n_in,
                              void* d_out, int out_size, void* d_ws, size_t ws_size,
                              hipStream_t stream) {
    const float* x   = (const float*)d_in[0];
    const float* w1  = (const float*)d_in[1];
    const float* b1  = (const float*)d_in[2];
    const float* wsc = (const float*)d_in[3];
    const float* bsc = (const float*)d_in[4];
    const float* wlc = (const float*)d_in[5];
    const float* blc = (const float*)d_in[6];
    float* out = (float*)d_out;
    char* ws = (char*)d_ws;

    float* wr2                = (float*)(ws + 0);                       //  9,437,184
    float* mid                = (float*)(ws + 9437184);                 // 67,108,864
    double* fgbuf             = (double*)(ws + 76546048);               //  2,359,296
    unsigned long long* keys  = (unsigned long long*)(ws + 78905344);   //  2,359,296
    unsigned long long* kth   = (unsigned long long*)(ws + 81264640);   //        64 (pad 512)
    unsigned int* cnt         = (unsigned int*)(ws + 81265152);         //        32 (pad 512)
    unsigned long long* cbuf  = (unsigned long long*)(ws + 81265664);   //    524,288
    float* bsort              = (float*)(ws + 81789952);                //    768,000
    unsigned char* vflag      = (unsigned char*)(ws + 82557952);        //     48,128
    unsigned long long* masks = (unsigned long long*)(ws + 82606080);   // 36,096,000 -> ~118.7MB

    hipMemsetAsync(cnt, 0, 8 * 4, stream);

    dim3 gw(128, 8);
    k_wreord<<<gw, 256, 0, stream>>>(w1, wr2);
    dim3 g3(16, 8, 8);
    k_conv3<<<g3, 256, 0, stream>>>(x, wr2, b1, mid);
    dim3 g1(64, 8);
    k_conv1<<<g1, 256, 0, stream>>>(mid, wlc, blc, wsc, bsc, out, fgbuf);
    k_keys<<<1152, 256, 0, stream>>>(out, fgbuf, keys);
    k_select<<<8, 1024, 0, stream>>>(keys, kth);
    k_compact<<<1152, 256, 0, stream>>>(keys, kth, cbuf, cnt);
    k_sort<<<8, 1024, 0, stream>>>(cbuf, out, bsort, vflag);
    dim3 gm(24, 6, 8);
    k_mask<<<gm, 256, 0, stream>>>(bsort, masks);
    k_scan<<<8, 128, 0, stream>>>(masks, vflag, bsort, out);
    k_anchor<<<144, 256, 0, stream>>>(out);
}